// Round 13
// baseline (285.826 us; speedup 1.0000x reference)
//
#include <hip/hip_runtime.h>
#include <math.h>

#define CDIM 256
#define NSEQ 4096
#define HWDIM 64
#define PPIX 4356   // 66*66 padded pixels

typedef unsigned short u16;
typedef __attribute__((ext_vector_type(8))) short bf16x8;
typedef __attribute__((ext_vector_type(4))) float f32x4;
typedef __attribute__((ext_vector_type(16))) float f32x16;

__device__ __forceinline__ u16 f2bf(float f) {
    unsigned u = __float_as_uint(f);
    unsigned r = (u + 0x7FFFu + ((u >> 16) & 1u)) >> 16;   // RN-even
    return (u16)r;
}

// async global->LDS, 16B per lane; LDS dest = wave-uniform base + lane*16
__device__ __forceinline__ void gload_lds16(const u16* g, u16* l) {
    __builtin_amdgcn_global_load_lds(
        (const __attribute__((address_space(1))) unsigned int*)g,
        (__attribute__((address_space(3))) unsigned int*)l, 16, 0, 0);
}

// ---------------------------------------------------------------------------
// pad+transpose: ref fp32 NCHW -> padded bf16 [b][pp][c], pp=(y+1)*66+(x+1)
// ---------------------------------------------------------------------------
__global__ __launch_bounds__(256)
void pad_transpose_kernel(const float* __restrict__ x, u16* __restrict__ padded)
{
    __shared__ float lds[64 * 65];
    const int tid = threadIdx.x;
    const int y = blockIdx.x, c0 = blockIdx.y << 6, b = blockIdx.z;
    #pragma unroll
    for (int i = 0; i < 16; ++i) {
        int f = tid + (i << 8);
        int c = f >> 6, xx = f & 63;
        lds[c * 65 + xx] = x[(((size_t)(b * CDIM + c0 + c)) * HWDIM + y) * HWDIM + xx];
    }
    __syncthreads();
    #pragma unroll
    for (int i = 0; i < 2; ++i) {
        int f = tid + (i << 8);
        int xx = f >> 3, c8 = f & 7;
        union { u16 h[8]; float4 v; } pk;
        #pragma unroll
        for (int j = 0; j < 8; ++j) pk.h[j] = f2bf(lds[(c8 * 8 + j) * 65 + xx]);
        *(float4*)&padded[((size_t)b * PPIX + (y + 1) * 66 + (xx + 1)) * CDIM + c0 + (c8 << 3)] = pk.v;
    }
}

// ---------------------------------------------------------------------------
// weight prepack: w fp32 [co][ci][3][3] -> wk bf16 [kyx][co][ci]
// ---------------------------------------------------------------------------
__global__ __launch_bounds__(256)
void w_prepack_kernel(const float* __restrict__ w, u16* __restrict__ wk)
{
    int t = (blockIdx.x << 8) + threadIdx.x;
    const float* wp = w + (size_t)t * 9;
    #pragma unroll
    for (int j = 0; j < 9; ++j) wk[j * 65536 + t] = f2bf(wp[j]);
}

// ---------------------------------------------------------------------------
// conv3x3+ReLU as 9 offset-GEMMs, double-buffered via global_load_lds (R12).
// ---------------------------------------------------------------------------
__device__ __forceinline__ void conv_stage(const u16* __restrict__ padded,
                                           const u16* __restrict__ wk,
                                           u16* Xb, u16* Wb,
                                           int b, int y0, int cb, int t,
                                           int wv, int lane)
{
    const int kyx = t >> 2, cib = (t & 3) << 6;
    const int ky = kyx / 3, kx = kyx - ky * 3;
    #pragma unroll
    for (int i = 0; i < 2; ++i) {
        int f = ((i << 2) + wv) << 6;
        int fl = f + lane;
        int r = fl >> 3;
        int gsw = (fl & 7) ^ (r & 7);
        gload_lds16(&padded[((size_t)b * PPIX + (y0 + ky) * 66 + r + kx) * CDIM + cib + (gsw << 3)],
                    Xb + (f << 3));
    }
    #pragma unroll
    for (int i = 0; i < 4; ++i) {
        int f = ((i << 2) + wv) << 6;
        int fl = f + lane;
        int r = fl >> 3;
        int gsw = (fl & 7) ^ (r & 7);
        gload_lds16(&wk[((size_t)kyx << 16) + (size_t)(cb + r) * 256 + cib + (gsw << 3)],
                    Wb + (f << 3));
    }
}

template <bool OA>
__global__ __launch_bounds__(256)
void conv_mfma_kernel(const u16* __restrict__ padded, const u16* __restrict__ wk,
                      u16* __restrict__ out)
{
    __shared__ alignas(16) u16 smem[24576];    // [X0 4096][X1 4096][W0 8192][W1 8192]

    const int tid = threadIdx.x;
    const int lane = tid & 63, wv = tid >> 6;
    const int lr = lane & 15, lg = lane >> 4;
    const int cb = blockIdx.x << 7;
    const int y0 = blockIdx.y;
    const int b = blockIdx.z;

    constexpr int MF = OA ? 4 : 2;
    constexpr int NF = OA ? 2 : 4;
    f32x4 acc[MF][NF] = {};

    conv_stage(padded, wk, smem, smem + 8192, b, y0, cb, 0, wv, lane);
    __syncthreads();

    int cur = 0;
    for (int t = 0; t < 36; ++t) {
        if (t + 1 < 36)
            conv_stage(padded, wk, smem + (cur ^ 1) * 4096,
                       smem + 8192 + (cur ^ 1) * 8192, b, y0, cb, t + 1, wv, lane);

        const u16* Xs = smem + cur * 4096;
        const u16* Ws = smem + 8192 + cur * 8192;

        #pragma unroll
        for (int kk = 0; kk < 2; ++kk) {
            const int ca = ((kk << 5) + (lg << 3)) ^ ((lr & 7) << 3);
            if constexpr (OA) {
                bf16x8 a[4], bb[2];
                #pragma unroll
                for (int mf = 0; mf < 4; ++mf)
                    a[mf] = *(const bf16x8*)&Xs[((mf * 16 + lr) << 6) + ca];
                #pragma unroll
                for (int nf = 0; nf < 2; ++nf)
                    bb[nf] = *(const bf16x8*)&Ws[((wv * 32 + nf * 16 + lr) << 6) + ca];
                #pragma unroll
                for (int mf = 0; mf < 4; ++mf)
                    #pragma unroll
                    for (int nf = 0; nf < 2; ++nf)
                        acc[mf][nf] = __builtin_amdgcn_mfma_f32_16x16x32_bf16(a[mf], bb[nf], acc[mf][nf], 0, 0, 0);
            } else {
                bf16x8 a[2], bb[4];
                #pragma unroll
                for (int mf = 0; mf < 2; ++mf)
                    a[mf] = *(const bf16x8*)&Ws[((wv * 32 + mf * 16 + lr) << 6) + ca];
                #pragma unroll
                for (int nf = 0; nf < 4; ++nf)
                    bb[nf] = *(const bf16x8*)&Xs[((nf * 16 + lr) << 6) + ca];
                #pragma unroll
                for (int mf = 0; mf < 2; ++mf)
                    #pragma unroll
                    for (int nf = 0; nf < 4; ++nf)
                        acc[mf][nf] = __builtin_amdgcn_mfma_f32_16x16x32_bf16(a[mf], bb[nf], acc[mf][nf], 0, 0, 0);
            }
        }
        __syncthreads();
        cur ^= 1;
    }

    const int m0 = y0 << 6;
    if constexpr (OA) {
        #pragma unroll
        for (int mf = 0; mf < 4; ++mf)
            #pragma unroll
            for (int nf = 0; nf < 2; ++nf) {
                int nb = m0 + mf * 16 + lg * 4;
                int co = cb + wv * 32 + nf * 16 + lr;
                union { u16 h[4]; uint2 v; } pk;
                #pragma unroll
                for (int j = 0; j < 4; ++j) pk.h[j] = f2bf(fmaxf(acc[mf][nf][j], 0.f));
                *(uint2*)&out[((size_t)(b * CDIM + co)) * NSEQ + nb] = pk.v;
            }
    } else {
        #pragma unroll
        for (int mf = 0; mf < 2; ++mf)
            #pragma unroll
            for (int nf = 0; nf < 4; ++nf) {
                int cob = cb + wv * 32 + mf * 16 + lg * 4;
                int n = m0 + nf * 16 + lr;
                union { u16 h[4]; uint2 v; } pk;
                #pragma unroll
                for (int j = 0; j < 4; ++j) pk.h[j] = f2bf(fmaxf(acc[mf][nf][j], 0.f));
                *(uint2*)&out[((size_t)(b * NSEQ + n)) * CDIM + cob] = pk.v;
            }
    }
}

// ---------------------------------------------------------------------------
// rownorm / maxred (no atomics, R10)
// ---------------------------------------------------------------------------
__global__ __launch_bounds__(256)
void rownorm_kernel(const u16* __restrict__ XT, float* __restrict__ rn2,
                    float* __restrict__ bmax)
{
    __shared__ float wmax[4];
    const int tid = threadIdx.x;
    const int lane = tid & 63, wv = tid >> 6;
    const int row = (blockIdx.x << 2) + wv;
    const u16* xp = &XT[(size_t)row * CDIM + (lane << 2)];
    uint2 v = *(const uint2*)xp;
    float s = 0.f;
    #pragma unroll
    for (int j = 0; j < 4; ++j) {
        unsigned hu = (j & 1) ? ((&v.x)[j >> 1] >> 16) : ((&v.x)[j >> 1] & 0xFFFFu);
        float x = __uint_as_float(hu << 16);
        s += x * x;
    }
    #pragma unroll
    for (int off = 1; off < 64; off <<= 1) s += __shfl_xor(s, off);
    if (lane == 0) {
        rn2[row] = s;
        wmax[wv] = s;
    }
    __syncthreads();
    if (tid == 0)
        bmax[blockIdx.x] = fmaxf(fmaxf(wmax[0], wmax[1]), fmaxf(wmax[2], wmax[3]));
}

__global__ __launch_bounds__(256)
void maxred_kernel(const float* __restrict__ bmax, float* __restrict__ maxrn2)
{
    __shared__ float wred[4];
    const int tid = threadIdx.x;
    const int lane = tid & 63, wv = tid >> 6;
    const int b = blockIdx.x;
    float m = 0.f;
    #pragma unroll
    for (int i = 0; i < 4; ++i)
        m = fmaxf(m, bmax[(b << 10) + (i << 8) + tid]);
    #pragma unroll
    for (int off = 1; off < 64; off <<= 1) m = fmaxf(m, __shfl_xor(m, off));
    if (lane == 0) wred[wv] = m;
    __syncthreads();
    if (tid == 0)
        maxrn2[b] = fmaxf(fmaxf(wred[0], wred[1]), fmaxf(wred[2], wred[3]));
}

// ---------------------------------------------------------------------------
// Flash attention partials: 16 waves (1024 thr), NC=128 chunks, 2-way key
// split, static-bound softmax (Cauchy-Schwarz m_ub), 32x32x16 MFMA.
// QK roles: 4 qt x 4 kh (32 keys each). PV roles: 8 ct x 2 qp (2 tiles/wave).
// Single-buffered K/V/P = 160 KB LDS; counted vmcnt(4) lets V land under QK.
// 4 waves/SIMD (occupancy play). lsum: 8 streams (2h x 4kh).
// ---------------------------------------------------------------------------
#define M_TILE 128
#define NC 128
#define NCHUNKS 16

// LDS map (u16 units): K [128 key][256 c] (4-bit swz) @0 (64 KB);
// V [256 c][128 n] (3-bit swz) @32768 (64 KB); P [128 q][128 k] @65536 (32 KB)
#define VS_OFF 32768
#define P_OFF  65536

__device__ __forceinline__ void stage_chunk128(const u16* __restrict__ XT,
                                               const u16* __restrict__ Vn,
                                               u16* Kb, u16* Vb,
                                               int b, int n0, int wid, int lane)
{
    #pragma unroll
    for (int i = 0; i < 4; ++i) {                // K: 4096 16B-units
        int f = ((i << 4) + wid) << 6;
        int fl = f + lane;
        int r = fl >> 5;                          // key 0..127
        int gsw = (fl & 31) ^ (r & 15);           // 4-bit pre-swizzle
        gload_lds16(&XT[(size_t)(b * NSEQ + n0 + r) * CDIM + (gsw << 3)], Kb + (f << 3));
    }
    #pragma unroll
    for (int i = 0; i < 4; ++i) {                // V: 4096 16B-units
        int f = ((i << 4) + wid) << 6;
        int fl = f + lane;
        int r = fl >> 4;                          // c 0..255
        int gsw = (fl & 15) ^ (r & 7);            // 3-bit pre-swizzle
        gload_lds16(&Vn[(size_t)(b * CDIM + r) * NSEQ + n0 + (gsw << 3)], Vb + (f << 3));
    }
}

__global__ __launch_bounds__(1024, 4)
void attn_part_kernel(const u16* __restrict__ XT, const u16* __restrict__ Vn,
                      const float* __restrict__ rn2, const float* __restrict__ maxrn2,
                      float* __restrict__ o0, u16* __restrict__ o1,
                      float* __restrict__ lsum)
{
    __shared__ alignas(16) u16 smem[81920];     // 160 KB exactly
    u16* Ps = smem + P_OFF;

    const int tid = threadIdx.x;
    const int lane = tid & 63;
    const int wid = tid >> 6;                   // 0..15
    const int l31 = lane & 31;
    const int hi = lane >> 5;
    const int bh = blockIdx.x;                  // b*2+h
    const int b = bh >> 1, h = bh & 1;
    const int m0 = blockIdx.y * M_TILE;
    const int nbase = h * (NSEQ / 2);

    // QK roles
    const int qt = wid & 3;                     // q-tile (32 q)
    const int kh = wid >> 2;                    // key quarter of the 128-chunk
    const int qa = qt * 32 + l31;               // block-local query
    // PV roles
    const int ct = wid >> 1;                    // c-tile (32 c), 0..7
    const int qp = wid & 1;                     // q-tile pair

    // static softmax offset: m_ub(q) = ||x_q|| * max_n ||x_n||  (>= all logits)
    const float mq = sqrtf(rn2[(size_t)b * NSEQ + m0 + qa]) * sqrtf(maxrn2[b]);

    // Q as B-operand frags in registers: k = ks*16 + hi*8 + j
    bf16x8 qreg[16];
    {
        const u16* qrow = &XT[(size_t)(b * NSEQ + m0 + qa) * CDIM + (hi << 3)];
        #pragma unroll
        for (int ks = 0; ks < 16; ++ks)
            qreg[ks] = *(const bf16x8*)(qrow + (ks << 4));
    }

    f32x16 o[2] = {};                           // 2 PV tiles (ct, qp*2+qi)
    float lrun = 0.f;                           // own (h,kh) partial denominator

    for (int ci = 0; ci < NCHUNKS; ++ci) {
        // stage current chunk (prev PV reads done at loop-end barrier)
        stage_chunk128(XT, Vn, smem, smem + VS_OFF, b, nbase + ci * NC, wid, lane);
        asm volatile("s_waitcnt vmcnt(4)" ::: "memory");   // K landed; V in flight
        __builtin_amdgcn_s_barrier();
        __builtin_amdgcn_sched_barrier(0);

        // ---- QK^T: s = D[key][q], key = kh*32 + rowmap, q = qt*32 + l31 ----
        f32x16 s = {};
        {
            const int krow = kh * 32 + l31;
            const u16* kbase = &smem[krow << 8];
            const int ksw = krow & 15;
            __builtin_amdgcn_s_setprio(1);
            #pragma unroll
            for (int ks = 0; ks < 16; ++ks) {
                bf16x8 ka = *(const bf16x8*)&kbase[(((ks << 1) + hi) ^ ksw) << 3];
                s = __builtin_amdgcn_mfma_f32_32x32x16_bf16(ka, qreg[ks], s, 0, 0, 0);
            }
            __builtin_amdgcn_s_setprio(0);
        }

        // ---- p = exp(s - m_ub): branchless, no max tree, no exchange ----
        float p[16];
        float ps = 0.f;
        #pragma unroll
        for (int r = 0; r < 16; ++r) { p[r] = __expf(s[r] - mq); ps += p[r]; }
        ps += __shfl_xor(ps, 32);
        lrun += ps;

        // ---- P -> LDS [q][key^swz], packed b64 writes ----
        {
            const int swz = qa & 7;
            #pragma unroll
            for (int r4 = 0; r4 < 4; ++r4) {
                union { u16 h4[4]; uint2 v; } pk;
                pk.h4[0] = f2bf(p[r4 * 4 + 0]); pk.h4[1] = f2bf(p[r4 * 4 + 1]);
                pk.h4[2] = f2bf(p[r4 * 4 + 2]); pk.h4[3] = f2bf(p[r4 * 4 + 3]);
                int g = (kh << 2) + r4;                  // key group of 8
                *(uint2*)&Ps[(qa << 7) + (((g ^ swz) << 3) | (hi << 2))] = pk.v;
            }
        }
        __syncthreads();                        // B: P visible; V landed (vmcnt0)

        // ---- PV: O^T[c][q] += V^T[c][n] P[n][q], 2 tiles/wave, V reused ----
        {
            const int crow = ct * 32 + l31;
            const u16* vbase = &smem[VS_OFF + (crow << 7)];
            const int csw = crow & 7;
            const int q0 = (qp * 2 + 0) * 32 + l31;
            const int q1 = (qp * 2 + 1) * 32 + l31;
            __builtin_amdgcn_s_setprio(1);
            #pragma unroll
            for (int ks = 0; ks < 8; ++ks) {
                const int gp = (ks << 1) + hi;          // n-group 0..15
                bf16x8 va  = *(const bf16x8*)&vbase[((gp ^ csw) << 3)];
                bf16x8 pb0 = *(const bf16x8*)&Ps[(q0 << 7) + ((gp ^ (q0 & 7)) << 3)];
                bf16x8 pb1 = *(const bf16x8*)&Ps[(q1 << 7) + ((gp ^ (q1 & 7)) << 3)];
                o[0] = __builtin_amdgcn_mfma_f32_32x32x16_bf16(va, pb0, o[0], 0, 0, 0);
                o[1] = __builtin_amdgcn_mfma_f32_32x32x16_bf16(va, pb1, o[1], 0, 0, 0);
            }
            __builtin_amdgcn_s_setprio(0);
        }

        __syncthreads();                        // C: PV reads done, LDS reusable
    }

    // ---- l per query, per (h,kh) stream (8 streams) ----
    if (lane < 32)
        lsum[(size_t)((h * 4 + kh) * 4 + b) * NSEQ + m0 + qa] = lrun;

    // ---- partial store: D[c][q] frags -> [b][c][m] directly ----
    #pragma unroll
    for (int qi = 0; qi < 2; ++qi) {
        const int q = m0 + (qp * 2 + qi) * 32 + l31;
        #pragma unroll
        for (int reg = 0; reg < 16; ++reg) {
            int c = ct * 32 + (reg & 3) + ((reg >> 2) << 3) + (hi << 2);
            size_t oi = ((size_t)(b * CDIM + c)) * NSEQ + q;
            if (h == 0) o0[oi] = o[qi][reg];
            else        o1[oi] = f2bf(o[qi][reg]);
        }
    }
}

// ---------------------------------------------------------------------------
// merge: out[i] = g * (O0[i] + O1[i]) / (sum of 8 lsum streams) + ref[i]
// ---------------------------------------------------------------------------
__global__ __launch_bounds__(256)
void merge_kernel(float* __restrict__ out, const u16* __restrict__ o1,
                  const float* __restrict__ lsum, const float* __restrict__ ref,
                  const float* __restrict__ gptr)
{
    const int f = (blockIdx.x << 8) + threadIdx.x;   // per float4 of out
    const int n4 = f & 1023;
    const int c = (f >> 10) & 255;
    const int b = f >> 18;
    const float g = gptr[0];

    float4 p0 = ((const float4*)out)[f];
    uint2 q1 = *(const uint2*)&o1[((size_t)(b * CDIM + c)) * NSEQ + (n4 << 2)];
    float4 rf = ((const float4*)ref)[f];

    float res[4];
    #pragma unroll
    for (int j = 0; j < 4; ++j) {
        int row = (n4 << 2) + j;
        float l = 0.f;
        #pragma unroll
        for (int sidx = 0; sidx < 8; ++sidx)
            l += lsum[(size_t)(sidx * 4 + b) * NSEQ + row];
        float rl = 1.0f / l;
        float v0 = ((const float*)&p0)[j];
        unsigned hu = ((j & 1) ? ((&q1.x)[j >> 1] >> 16) : ((&q1.x)[j >> 1] & 0xFFFFu));
        float v1 = __uint_as_float(hu << 16);
        float a = (v0 + v1) * rl;
        res[j] = g * a + ((const float*)&rf)[j];
    }
    ((float4*)out)[f] = *(float4*)res;
}

// ---------------------------------------------------------------------------
extern "C" void kernel_launch(void* const* d_in, const int* in_sizes, int n_in,
                              void* d_out, int out_size, void* d_ws, size_t ws_size,
                              hipStream_t stream)
{
    // dict order: inputs, ref, w1, w2, gamma (dead conv on `inputs` skipped)
    const float* ref = (const float*)d_in[1];
    const float* w1  = (const float*)d_in[2];
    const float* w2  = (const float*)d_in[3];
    const float* gma = (const float*)d_in[4];
    float* out = (float*)d_out;

    u16* XT     = (u16*)d_ws;                          // [B][N][C] bf16 (Q=K)  8.39 MB
    u16* Vn     = XT + (size_t)4 * NSEQ * CDIM;        // [B][C][N] bf16 (V)    8.39 MB
    u16* padded = Vn + (size_t)4 * NSEQ * CDIM;        // [B][4356][256] bf16   8.9 MB (dead after convs)
    u16* wk1    = padded + (size_t)4 * PPIX * CDIM;    // 1.18 MB (dead after convs)
    u16* wk2    = wk1 + (size_t)9 * 65536;             // 1.18 MB (dead after convs)
    // attn-phase reuse of dead regions:
    u16*   o1     = padded;                            // [B][C][N] bf16 partial (8.39 MB)
    float* lsum   = (float*)wk1;                       // [8][B][N] f32 (0.52 MB)
    float* rn2    = (float*)wk2;                       // [B][N] f32 (64 KB)
    float* bmax   = rn2 + 16384;                       // [4096] f32 (16 KB)
    float* maxrn2 = bmax + 4096;                       // [4] f32

    hipMemsetAsync(padded, 0, (size_t)4 * PPIX * CDIM * sizeof(u16), stream);
    pad_transpose_kernel<<<dim3(64, 4, 4), 256, 0, stream>>>(ref, padded);
    w_prepack_kernel<<<dim3(256), 256, 0, stream>>>(w1, wk1);
    w_prepack_kernel<<<dim3(256), 256, 0, stream>>>(w2, wk2);

    dim3 cgrid(2, 64, 4);
    conv_mfma_kernel<false><<<cgrid, 256, 0, stream>>>(padded, wk1, XT);  // -> XT
    conv_mfma_kernel<true ><<<cgrid, 256, 0, stream>>>(padded, wk2, Vn);  // -> Vn

    rownorm_kernel<<<dim3(4096), 256, 0, stream>>>(XT, rn2, bmax);        // no atomics
    maxred_kernel<<<dim3(4), 256, 0, stream>>>(bmax, maxrn2);

    attn_part_kernel<<<dim3(8, NSEQ / M_TILE), 1024, 0, stream>>>(XT, Vn, rn2, maxrn2, out, o1, lsum);
    merge_kernel<<<dim3((4 * CDIM * NSEQ / 4) / 256), 256, 0, stream>>>(out, o1, lsum, ref, gma);
}

// Round 14
// 159.038 us; speedup vs baseline: 1.7972x; 1.7972x over previous
//
#include <hip/hip_runtime.h>
#include <math.h>

#define CDIM 256
#define NSEQ 4096
#define HWDIM 64
#define PPIX 4356   // 66*66 padded pixels

typedef unsigned short u16;
typedef __attribute__((ext_vector_type(8))) short bf16x8;
typedef __attribute__((ext_vector_type(4))) float f32x4;
typedef __attribute__((ext_vector_type(16))) float f32x16;

__device__ __forceinline__ u16 f2bf(float f) {
    unsigned u = __float_as_uint(f);
    unsigned r = (u + 0x7FFFu + ((u >> 16) & 1u)) >> 16;   // RN-even
    return (u16)r;
}

// async global->LDS, 16B per lane; LDS dest = wave-uniform base + lane*16
__device__ __forceinline__ void gload_lds16(const u16* g, u16* l) {
    __builtin_amdgcn_global_load_lds(
        (const __attribute__((address_space(1))) unsigned int*)g,
        (__attribute__((address_space(3))) unsigned int*)l, 16, 0, 0);
}

// ---------------------------------------------------------------------------
// pad+transpose: ref fp32 NCHW -> padded bf16 [b][pp][c], pp=(y+1)*66+(x+1)
// ---------------------------------------------------------------------------
__global__ __launch_bounds__(256)
void pad_transpose_kernel(const float* __restrict__ x, u16* __restrict__ padded)
{
    __shared__ float lds[64 * 65];
    const int tid = threadIdx.x;
    const int y = blockIdx.x, c0 = blockIdx.y << 6, b = blockIdx.z;
    #pragma unroll
    for (int i = 0; i < 16; ++i) {
        int f = tid + (i << 8);
        int c = f >> 6, xx = f & 63;
        lds[c * 65 + xx] = x[(((size_t)(b * CDIM + c0 + c)) * HWDIM + y) * HWDIM + xx];
    }
    __syncthreads();
    #pragma unroll
    for (int i = 0; i < 2; ++i) {
        int f = tid + (i << 8);
        int xx = f >> 3, c8 = f & 7;
        union { u16 h[8]; float4 v; } pk;
        #pragma unroll
        for (int j = 0; j < 8; ++j) pk.h[j] = f2bf(lds[(c8 * 8 + j) * 65 + xx]);
        *(float4*)&padded[((size_t)b * PPIX + (y + 1) * 66 + (xx + 1)) * CDIM + c0 + (c8 << 3)] = pk.v;
    }
}

// ---------------------------------------------------------------------------
// weight prepack (both): w fp32 [co][ci][3][3] -> wk bf16 [kyx][co][ci]
// ---------------------------------------------------------------------------
__global__ __launch_bounds__(256)
void w_prepack2_kernel(const float* __restrict__ w1, const float* __restrict__ w2,
                       u16* __restrict__ wk1, u16* __restrict__ wk2)
{
    int g = (blockIdx.x << 8) + threadIdx.x;     // 0..131071
    int t = g & 65535;
    const float* wp = (g < 65536 ? w1 : w2) + (size_t)t * 9;
    u16* wk = (g < 65536 ? wk1 : wk2);
    #pragma unroll
    for (int j = 0; j < 9; ++j) wk[j * 65536 + t] = f2bf(wp[j]);
}

// ---------------------------------------------------------------------------
// FUSED dual conv3x3+ReLU as 9 offset-GEMMs, double-buffered global_load_lds.
// One X staging serves both convs (Xs frags are conv1's B AND conv2's A).
// conv1 -> XT[b][n][co] (D[co][n]); conv2 -> Vn[b][co][n] (D[n][co]).
// LDS: X dbuf 2x8KB + W1 dbuf 2x16KB + W2 dbuf 2x16KB = 80 KB.
// grid (2 cb, 64 y, 4 b) = 512 blocks, 256 thr.
// ---------------------------------------------------------------------------
#define CW1_OFF 8192
#define CW2_OFF 24576

__device__ __forceinline__ void conv_stage2(const u16* __restrict__ padded,
                                            const u16* __restrict__ wk1,
                                            const u16* __restrict__ wk2,
                                            u16* Xb, u16* W1b, u16* W2b,
                                            int b, int y0, int cb, int t,
                                            int wv, int lane)
{
    const int kyx = t >> 2, cib = (t & 3) << 6;
    const int ky = kyx / 3, kx = kyx - ky * 3;
    #pragma unroll
    for (int i = 0; i < 2; ++i) {
        int f = ((i << 2) + wv) << 6;
        int fl = f + lane;
        int r = fl >> 3;
        int gsw = (fl & 7) ^ (r & 7);
        gload_lds16(&padded[((size_t)b * PPIX + (y0 + ky) * 66 + r + kx) * CDIM + cib + (gsw << 3)],
                    Xb + (f << 3));
    }
    #pragma unroll
    for (int i = 0; i < 4; ++i) {
        int f = ((i << 2) + wv) << 6;
        int fl = f + lane;
        int r = fl >> 3;
        int gsw = (fl & 7) ^ (r & 7);
        gload_lds16(&wk1[((size_t)kyx << 16) + (size_t)(cb + r) * 256 + cib + (gsw << 3)],
                    W1b + (f << 3));
    }
    #pragma unroll
    for (int i = 0; i < 4; ++i) {
        int f = ((i << 2) + wv) << 6;
        int fl = f + lane;
        int r = fl >> 3;
        int gsw = (fl & 7) ^ (r & 7);
        gload_lds16(&wk2[((size_t)kyx << 16) + (size_t)(cb + r) * 256 + cib + (gsw << 3)],
                    W2b + (f << 3));
    }
}

__global__ __launch_bounds__(256)
void conv_dual_kernel(const u16* __restrict__ padded,
                      const u16* __restrict__ wk1, const u16* __restrict__ wk2,
                      u16* __restrict__ XT, u16* __restrict__ Vn)
{
    __shared__ alignas(16) u16 smem[40960];    // 80 KB

    const int tid = threadIdx.x;
    const int lane = tid & 63, wv = tid >> 6;
    const int lr = lane & 15, lg = lane >> 4;
    const int cb = blockIdx.x << 7;
    const int y0 = blockIdx.y;
    const int b = blockIdx.z;

    f32x4 acc1[2][4] = {};   // conv1: D[co][n]
    f32x4 acc2[4][2] = {};   // conv2: D[n][co]

    conv_stage2(padded, wk1, wk2, smem, smem + CW1_OFF, smem + CW2_OFF,
                b, y0, cb, 0, wv, lane);
    __syncthreads();

    int cur = 0;
    for (int t = 0; t < 36; ++t) {
        if (t + 1 < 36)
            conv_stage2(padded, wk1, wk2, smem + (cur ^ 1) * 4096,
                        smem + CW1_OFF + (cur ^ 1) * 8192,
                        smem + CW2_OFF + (cur ^ 1) * 8192,
                        b, y0, cb, t + 1, wv, lane);

        const u16* Xs  = smem + cur * 4096;
        const u16* Ws1 = smem + CW1_OFF + cur * 8192;
        const u16* Ws2 = smem + CW2_OFF + cur * 8192;

        #pragma unroll
        for (int kk = 0; kk < 2; ++kk) {
            const int ca = ((kk << 5) + (lg << 3)) ^ ((lr & 7) << 3);
            bf16x8 xs[4];
            #pragma unroll
            for (int nf = 0; nf < 4; ++nf)
                xs[nf] = *(const bf16x8*)&Xs[((nf * 16 + lr) << 6) + ca];
            bf16x8 w1f[2], w2f[2];
            #pragma unroll
            for (int mf = 0; mf < 2; ++mf) {
                w1f[mf] = *(const bf16x8*)&Ws1[((wv * 32 + mf * 16 + lr) << 6) + ca];
                w2f[mf] = *(const bf16x8*)&Ws2[((wv * 32 + mf * 16 + lr) << 6) + ca];
            }
            #pragma unroll
            for (int mf = 0; mf < 2; ++mf)
                #pragma unroll
                for (int nf = 0; nf < 4; ++nf)
                    acc1[mf][nf] = __builtin_amdgcn_mfma_f32_16x16x32_bf16(w1f[mf], xs[nf], acc1[mf][nf], 0, 0, 0);
            #pragma unroll
            for (int mf = 0; mf < 4; ++mf)
                #pragma unroll
                for (int nf = 0; nf < 2; ++nf)
                    acc2[mf][nf] = __builtin_amdgcn_mfma_f32_16x16x32_bf16(xs[mf], w2f[nf], acc2[mf][nf], 0, 0, 0);
        }
        __syncthreads();
        cur ^= 1;
    }

    const int m0 = y0 << 6;
    // conv1 epilogue: D[co][n] -> XT[b][n][co]
    #pragma unroll
    for (int mf = 0; mf < 2; ++mf)
        #pragma unroll
        for (int nf = 0; nf < 4; ++nf) {
            int cob = cb + wv * 32 + mf * 16 + lg * 4;
            int n = m0 + nf * 16 + lr;
            union { u16 h[4]; uint2 v; } pk;
            #pragma unroll
            for (int j = 0; j < 4; ++j) pk.h[j] = f2bf(fmaxf(acc1[mf][nf][j], 0.f));
            *(uint2*)&XT[((size_t)(b * NSEQ + n)) * CDIM + cob] = pk.v;
        }
    // conv2 epilogue: D[n][co] -> Vn[b][co][n]
    #pragma unroll
    for (int mf = 0; mf < 4; ++mf)
        #pragma unroll
        for (int nf = 0; nf < 2; ++nf) {
            int nb = m0 + mf * 16 + lg * 4;
            int co = cb + wv * 32 + nf * 16 + lr;
            union { u16 h[4]; uint2 v; } pk;
            #pragma unroll
            for (int j = 0; j < 4; ++j) pk.h[j] = f2bf(fmaxf(acc2[mf][nf][j], 0.f));
            *(uint2*)&Vn[((size_t)(b * CDIM + co)) * NSEQ + nb] = pk.v;
        }
}

// ---------------------------------------------------------------------------
// rownorm / maxred (no atomics, R10)
// ---------------------------------------------------------------------------
__global__ __launch_bounds__(256)
void rownorm_kernel(const u16* __restrict__ XT, float* __restrict__ rn2,
                    float* __restrict__ bmax)
{
    __shared__ float wmax[4];
    const int tid = threadIdx.x;
    const int lane = tid & 63, wv = tid >> 6;
    const int row = (blockIdx.x << 2) + wv;
    const u16* xp = &XT[(size_t)row * CDIM + (lane << 2)];
    uint2 v = *(const uint2*)xp;
    float s = 0.f;
    #pragma unroll
    for (int j = 0; j < 4; ++j) {
        unsigned hu = (j & 1) ? ((&v.x)[j >> 1] >> 16) : ((&v.x)[j >> 1] & 0xFFFFu);
        float x = __uint_as_float(hu << 16);
        s += x * x;
    }
    #pragma unroll
    for (int off = 1; off < 64; off <<= 1) s += __shfl_xor(s, off);
    if (lane == 0) {
        rn2[row] = s;
        wmax[wv] = s;
    }
    __syncthreads();
    if (tid == 0)
        bmax[blockIdx.x] = fmaxf(fmaxf(wmax[0], wmax[1]), fmaxf(wmax[2], wmax[3]));
}

__global__ __launch_bounds__(256)
void maxred_kernel(const float* __restrict__ bmax, float* __restrict__ maxrn2)
{
    __shared__ float wred[4];
    const int tid = threadIdx.x;
    const int lane = tid & 63, wv = tid >> 6;
    const int b = blockIdx.x;
    float m = 0.f;
    #pragma unroll
    for (int i = 0; i < 4; ++i)
        m = fmaxf(m, bmax[(b << 10) + (i << 8) + tid]);
    #pragma unroll
    for (int off = 1; off < 64; off <<= 1) m = fmaxf(m, __shfl_xor(m, off));
    if (lane == 0) wred[wv] = m;
    __syncthreads();
    if (tid == 0)
        maxrn2[b] = fmaxf(fmaxf(wred[0], wred[1]), fmaxf(wred[2], wred[3]));
}

// ---------------------------------------------------------------------------
// Flash attention partials (R10 exact — proven 90us): 2-way key split,
// 32x32x16 MFMA, static-bound softmax (Cauchy-Schwarz m_ub), double-buffered
// global_load_lds staging. QK wave=(qt,kh); PV wave=(qsel,csel).
// ---------------------------------------------------------------------------
#define M_TILE 128
#define NC 64
#define NCHUNKS 32

#define KS_OFF 0        // 2 x [64 key][256 c]  (4-bit row XOR swizzle)
#define VS_OFF 32768    // 2 x [256 c][64 n]    (3-bit row XOR swizzle)
#define P_OFF  65536    // [128 q][64 key]      (3-bit row XOR swizzle)

__device__ __forceinline__ void stage_chunk(const u16* __restrict__ XT, const u16* __restrict__ Vn,
                                            u16* Kb, u16* Vb, int b, int n0, int wv, int lane)
{
    #pragma unroll
    for (int i = 0; i < 4; ++i) {
        int f = ((i << 3) + wv) << 6;
        int fl = f + lane;
        int r = fl >> 5;
        int gsw = (fl & 31) ^ (r & 15);
        gload_lds16(&XT[(size_t)(b * NSEQ + n0 + r) * CDIM + (gsw << 3)], Kb + (f << 3));
    }
    #pragma unroll
    for (int i = 0; i < 4; ++i) {
        int f = ((i << 3) + wv) << 6;
        int fl = f + lane;
        int r = fl >> 3;
        int gsw = (fl & 7) ^ (r & 7);
        gload_lds16(&Vn[(size_t)(b * CDIM + r) * NSEQ + n0 + (gsw << 3)], Vb + (f << 3));
    }
}

__global__ __launch_bounds__(512, 2)
void attn_part_kernel(const u16* __restrict__ XT, const u16* __restrict__ Vn,
                      const float* __restrict__ rn2, const float* __restrict__ maxrn2,
                      float* __restrict__ o0, u16* __restrict__ o1,
                      float* __restrict__ lsum)
{
    __shared__ alignas(16) u16 smem[73728];     // 147.5 KB
    u16* Ps = smem + P_OFF;

    const int tid = threadIdx.x;
    const int lane = tid & 63;
    const int wv = tid >> 6;
    const int l31 = lane & 31;
    const int hi = lane >> 5;
    const int bh = blockIdx.x;                  // b*2+h
    const int b = bh >> 1, h = bh & 1;
    const int m0 = blockIdx.y * M_TILE;
    const int nbase = h * (NSEQ / 2);

    const int qt = wv & 3;
    const int kh = wv >> 2;
    const int qa = qt * 32 + l31;
    const int qsel = wv & 1;
    const int csel = wv >> 1;

    const float mq = sqrtf(rn2[(size_t)b * NSEQ + m0 + qa]) * sqrtf(maxrn2[b]);

    bf16x8 qreg[16];
    {
        const u16* qrow = &XT[(size_t)(b * NSEQ + m0 + qa) * CDIM + (hi << 3)];
        #pragma unroll
        for (int ks = 0; ks < 16; ++ks)
            qreg[ks] = *(const bf16x8*)(qrow + (ks << 4));
    }

    f32x16 o[2][2] = {};
    float lrun = 0.f;

    stage_chunk(XT, Vn, smem + KS_OFF, smem + VS_OFF, b, nbase, wv, lane);
    __syncthreads();

    int cur = 0;
    for (int ci = 0; ci < NCHUNKS; ++ci) {
        if (ci + 1 < NCHUNKS)
            stage_chunk(XT, Vn, smem + KS_OFF + (cur ^ 1) * 16384,
                        smem + VS_OFF + (cur ^ 1) * 16384,
                        b, nbase + (ci + 1) * NC, wv, lane);

        const u16* Kc = smem + KS_OFF + cur * 16384;
        const u16* Vc = smem + VS_OFF + cur * 16384;

        // ---- QK^T ----
        f32x16 s = {};
        {
            const int krow = kh * 32 + l31;
            const u16* kbase = &Kc[krow << 8];
            const int ksw = krow & 15;
            #pragma unroll
            for (int ks = 0; ks < 16; ++ks) {
                bf16x8 ka = *(const bf16x8*)&kbase[(((ks << 1) + hi) ^ ksw) << 3];
                s = __builtin_amdgcn_mfma_f32_32x32x16_bf16(ka, qreg[ks], s, 0, 0, 0);
            }
        }

        // ---- p = exp(s - m_ub) ----
        float p[16];
        float ps = 0.f;
        #pragma unroll
        for (int r = 0; r < 16; ++r) { p[r] = __expf(s[r] - mq); ps += p[r]; }
        ps += __shfl_xor(ps, 32);
        lrun += ps;

        // ---- P -> LDS ----
        {
            const int swz = qa & 7;
            #pragma unroll
            for (int r4 = 0; r4 < 4; ++r4) {
                union { u16 h4[4]; uint2 v; } pk;
                pk.h4[0] = f2bf(p[r4 * 4 + 0]); pk.h4[1] = f2bf(p[r4 * 4 + 1]);
                pk.h4[2] = f2bf(p[r4 * 4 + 2]); pk.h4[3] = f2bf(p[r4 * 4 + 3]);
                int g = (kh << 2) + r4;
                *(uint2*)&Ps[(qa << 6) + (((g ^ swz) << 3) | (hi << 2))] = pk.v;
            }
        }
        __syncthreads();

        // ---- PV ----
        {
            const int q0 = ((qsel << 1) + 0) * 32 + l31;
            const int q1 = ((qsel << 1) + 1) * 32 + l31;
            const int c0 = ((csel << 1) + 0) * 32 + l31;
            const int c1 = ((csel << 1) + 1) * 32 + l31;
            #pragma unroll
            for (int ks = 0; ks < 4; ++ks) {
                const int gp = (ks << 1) + hi;
                bf16x8 pb0 = *(const bf16x8*)&Ps[(q0 << 6) + ((gp ^ (q0 & 7)) << 3)];
                bf16x8 pb1 = *(const bf16x8*)&Ps[(q1 << 6) + ((gp ^ (q1 & 7)) << 3)];
                bf16x8 va0 = *(const bf16x8*)&Vc[(c0 << 6) + ((gp ^ (c0 & 7)) << 3)];
                bf16x8 va1 = *(const bf16x8*)&Vc[(c1 << 6) + ((gp ^ (c1 & 7)) << 3)];
                o[0][0] = __builtin_amdgcn_mfma_f32_32x32x16_bf16(va0, pb0, o[0][0], 0, 0, 0);
                o[0][1] = __builtin_amdgcn_mfma_f32_32x32x16_bf16(va1, pb0, o[0][1], 0, 0, 0);
                o[1][0] = __builtin_amdgcn_mfma_f32_32x32x16_bf16(va0, pb1, o[1][0], 0, 0, 0);
                o[1][1] = __builtin_amdgcn_mfma_f32_32x32x16_bf16(va1, pb1, o[1][1], 0, 0, 0);
            }
        }

        __syncthreads();
        cur ^= 1;
    }

    if (lane < 32)
        lsum[(size_t)(((h * 2 + kh) * 4 + b)) * NSEQ + m0 + qa] = lrun;

    #pragma unroll
    for (int qi = 0; qi < 2; ++qi) {
        const int q = m0 + ((qsel << 1) + qi) * 32 + l31;
        #pragma unroll
        for (int cj = 0; cj < 2; ++cj) {
            #pragma unroll
            for (int reg = 0; reg < 16; ++reg) {
                int c = ((csel << 1) + cj) * 32 + (reg & 3) + ((reg >> 2) << 3) + (hi << 2);
                size_t oi = ((size_t)(b * CDIM + c)) * NSEQ + q;
                if (h == 0) o0[oi] = o[qi][cj][reg];
                else        o1[oi] = f2bf(o[qi][cj][reg]);
            }
        }
    }
}

// ---------------------------------------------------------------------------
// merge: out[i] = g * (O0[i] + O1[i]) / (l00+l01+l10+l11) + ref[i]
// ---------------------------------------------------------------------------
__global__ __launch_bounds__(256)
void merge_kernel(float* __restrict__ out, const u16* __restrict__ o1,
                  const float* __restrict__ lsum, const float* __restrict__ ref,
                  const float* __restrict__ gptr)
{
    const int f = (blockIdx.x << 8) + threadIdx.x;
    const int n4 = f & 1023;
    const int c = (f >> 10) & 255;
    const int b = f >> 18;
    const float g = gptr[0];

    float4 p0 = ((const float4*)out)[f];
    uint2 q1 = *(const uint2*)&o1[((size_t)(b * CDIM + c)) * NSEQ + (n4 << 2)];
    float4 rf = ((const float4*)ref)[f];

    float res[4];
    #pragma unroll
    for (int j = 0; j < 4; ++j) {
        int row = (n4 << 2) + j;
        float l = lsum[(size_t)(0 * 4 + b) * NSEQ + row]
                + lsum[(size_t)(1 * 4 + b) * NSEQ + row]
                + lsum[(size_t)(2 * 4 + b) * NSEQ + row]
                + lsum[(size_t)(3 * 4 + b) * NSEQ + row];
        float rl = 1.0f / l;
        float v0 = ((const float*)&p0)[j];
        unsigned hu = ((j & 1) ? ((&q1.x)[j >> 1] >> 16) : ((&q1.x)[j >> 1] & 0xFFFFu));
        float v1 = __uint_as_float(hu << 16);
        float a = (v0 + v1) * rl;
        res[j] = g * a + ((const float*)&rf)[j];
    }
    ((float4*)out)[f] = *(float4*)res;
}

// ---------------------------------------------------------------------------
extern "C" void kernel_launch(void* const* d_in, const int* in_sizes, int n_in,
                              void* d_out, int out_size, void* d_ws, size_t ws_size,
                              hipStream_t stream)
{
    // dict order: inputs, ref, w1, w2, gamma (dead conv on `inputs` skipped)
    const float* ref = (const float*)d_in[1];
    const float* w1  = (const float*)d_in[2];
    const float* w2  = (const float*)d_in[3];
    const float* gma = (const float*)d_in[4];
    float* out = (float*)d_out;

    u16* XT     = (u16*)d_ws;                          // [B][N][C] bf16 (Q=K)  8.39 MB
    u16* Vn     = XT + (size_t)4 * NSEQ * CDIM;        // [B][C][N] bf16 (V)    8.39 MB
    u16* padded = Vn + (size_t)4 * NSEQ * CDIM;        // [B][4356][256] bf16   8.9 MB (dead after convs)
    u16* wk1    = padded + (size_t)4 * PPIX * CDIM;    // 1.18 MB (dead after convs)
    u16* wk2    = wk1 + (size_t)9 * 65536;             // 1.18 MB (dead after convs)
    // attn-phase reuse of dead regions:
    u16*   o1     = padded;                            // [B][C][N] bf16 partial (8.39 MB)
    float* lsum   = (float*)wk1;                       // [4][B][N] f32 (0.26 MB)
    float* rn2    = (float*)wk2;                       // [B][N] f32 (64 KB)
    float* bmax   = rn2 + 16384;                       // [4096] f32 (16 KB)
    float* maxrn2 = bmax + 4096;                       // [4] f32

    hipMemsetAsync(padded, 0, (size_t)4 * PPIX * CDIM * sizeof(u16), stream);
    pad_transpose_kernel<<<dim3(64, 4, 4), 256, 0, stream>>>(ref, padded);
    w_prepack2_kernel<<<dim3(512), 256, 0, stream>>>(w1, w2, wk1, wk2);

    conv_dual_kernel<<<dim3(2, 64, 4), 256, 0, stream>>>(padded, wk1, wk2, XT, Vn);

    rownorm_kernel<<<dim3(4096), 256, 0, stream>>>(XT, rn2, bmax);        // no atomics
    maxred_kernel<<<dim3(4), 256, 0, stream>>>(bmax, maxrn2);

    attn_part_kernel<<<dim3(8, NSEQ / M_TILE), 512, 0, stream>>>(XT, Vn, rn2, maxrn2, out, o1, lsum);
    merge_kernel<<<dim3((4 * CDIM * NSEQ / 4) / 256), 256, 0, stream>>>(out, o1, lsum, ref, gma);
}

// Round 15
// 157.900 us; speedup vs baseline: 1.8102x; 1.0072x over previous
//
#include <hip/hip_runtime.h>
#include <math.h>

#define CDIM 256
#define NSEQ 4096
#define HWDIM 64
#define PPIX 4356   // 66*66 padded pixels

typedef unsigned short u16;
typedef __attribute__((ext_vector_type(8))) short bf16x8;
typedef __attribute__((ext_vector_type(4))) float f32x4;
typedef __attribute__((ext_vector_type(16))) float f32x16;

__device__ __forceinline__ u16 f2bf(float f) {
    unsigned u = __float_as_uint(f);
    unsigned r = (u + 0x7FFFu + ((u >> 16) & 1u)) >> 16;   // RN-even
    return (u16)r;
}

// async global->LDS, 16B per lane; LDS dest = wave-uniform base + lane*16
__device__ __forceinline__ void gload_lds16(const u16* g, u16* l) {
    __builtin_amdgcn_global_load_lds(
        (const __attribute__((address_space(1))) unsigned int*)g,
        (__attribute__((address_space(3))) unsigned int*)l, 16, 0, 0);
}

// ---------------------------------------------------------------------------
// pad+transpose: ref fp32 NCHW -> padded bf16 [b][pp][c], pp=(y+1)*66+(x+1)
// ---------------------------------------------------------------------------
__global__ __launch_bounds__(256)
void pad_transpose_kernel(const float* __restrict__ x, u16* __restrict__ padded)
{
    __shared__ float lds[64 * 65];
    const int tid = threadIdx.x;
    const int y = blockIdx.x, c0 = blockIdx.y << 6, b = blockIdx.z;
    #pragma unroll
    for (int i = 0; i < 16; ++i) {
        int f = tid + (i << 8);
        int c = f >> 6, xx = f & 63;
        lds[c * 65 + xx] = x[(((size_t)(b * CDIM + c0 + c)) * HWDIM + y) * HWDIM + xx];
    }
    __syncthreads();
    #pragma unroll
    for (int i = 0; i < 2; ++i) {
        int f = tid + (i << 8);
        int xx = f >> 3, c8 = f & 7;
        union { u16 h[8]; float4 v; } pk;
        #pragma unroll
        for (int j = 0; j < 8; ++j) pk.h[j] = f2bf(lds[(c8 * 8 + j) * 65 + xx]);
        *(float4*)&padded[((size_t)b * PPIX + (y + 1) * 66 + (xx + 1)) * CDIM + c0 + (c8 << 3)] = pk.v;
    }
}

// ---------------------------------------------------------------------------
// weight prepack (both): w fp32 [co][ci][3][3] -> wk bf16 [kyx][co][ci]
// ---------------------------------------------------------------------------
__global__ __launch_bounds__(256)
void w_prepack2_kernel(const float* __restrict__ w1, const float* __restrict__ w2,
                       u16* __restrict__ wk1, u16* __restrict__ wk2)
{
    int g = (blockIdx.x << 8) + threadIdx.x;     // 0..131071
    int t = g & 65535;
    const float* wp = (g < 65536 ? w1 : w2) + (size_t)t * 9;
    u16* wk = (g < 65536 ? wk1 : wk2);
    #pragma unroll
    for (int j = 0; j < 9; ++j) wk[j * 65536 + t] = f2bf(wp[j]);
}

// ---------------------------------------------------------------------------
// FUSED dual conv3x3+ReLU as 9 offset-GEMMs, double-buffered global_load_lds.
// One X staging serves both convs (Xs frags are conv1's B AND conv2's A).
// conv1 -> XT[b][n][co] (D[co][n]); conv2 -> Vn[b][co][n] (D[n][co]).
// LDS: X dbuf 2x8KB + W1 dbuf 2x16KB + W2 dbuf 2x16KB = 80 KB.
// ---------------------------------------------------------------------------
#define CW1_OFF 8192
#define CW2_OFF 24576

__device__ __forceinline__ void conv_stage2(const u16* __restrict__ padded,
                                            const u16* __restrict__ wk1,
                                            const u16* __restrict__ wk2,
                                            u16* Xb, u16* W1b, u16* W2b,
                                            int b, int y0, int cb, int t,
                                            int wv, int lane)
{
    const int kyx = t >> 2, cib = (t & 3) << 6;
    const int ky = kyx / 3, kx = kyx - ky * 3;
    #pragma unroll
    for (int i = 0; i < 2; ++i) {
        int f = ((i << 2) + wv) << 6;
        int fl = f + lane;
        int r = fl >> 3;
        int gsw = (fl & 7) ^ (r & 7);
        gload_lds16(&padded[((size_t)b * PPIX + (y0 + ky) * 66 + r + kx) * CDIM + cib + (gsw << 3)],
                    Xb + (f << 3));
    }
    #pragma unroll
    for (int i = 0; i < 4; ++i) {
        int f = ((i << 2) + wv) << 6;
        int fl = f + lane;
        int r = fl >> 3;
        int gsw = (fl & 7) ^ (r & 7);
        gload_lds16(&wk1[((size_t)kyx << 16) + (size_t)(cb + r) * 256 + cib + (gsw << 3)],
                    W1b + (f << 3));
    }
    #pragma unroll
    for (int i = 0; i < 4; ++i) {
        int f = ((i << 2) + wv) << 6;
        int fl = f + lane;
        int r = fl >> 3;
        int gsw = (fl & 7) ^ (r & 7);
        gload_lds16(&wk2[((size_t)kyx << 16) + (size_t)(cb + r) * 256 + cib + (gsw << 3)],
                    W2b + (f << 3));
    }
}

__global__ __launch_bounds__(256)
void conv_dual_kernel(const u16* __restrict__ padded,
                      const u16* __restrict__ wk1, const u16* __restrict__ wk2,
                      u16* __restrict__ XT, u16* __restrict__ Vn)
{
    __shared__ alignas(16) u16 smem[40960];    // 80 KB

    const int tid = threadIdx.x;
    const int lane = tid & 63, wv = tid >> 6;
    const int lr = lane & 15, lg = lane >> 4;
    const int cb = blockIdx.x << 7;
    const int y0 = blockIdx.y;
    const int b = blockIdx.z;

    f32x4 acc1[2][4] = {};   // conv1: D[co][n]
    f32x4 acc2[4][2] = {};   // conv2: D[n][co]

    conv_stage2(padded, wk1, wk2, smem, smem + CW1_OFF, smem + CW2_OFF,
                b, y0, cb, 0, wv, lane);
    __syncthreads();

    int cur = 0;
    for (int t = 0; t < 36; ++t) {
        if (t + 1 < 36)
            conv_stage2(padded, wk1, wk2, smem + (cur ^ 1) * 4096,
                        smem + CW1_OFF + (cur ^ 1) * 8192,
                        smem + CW2_OFF + (cur ^ 1) * 8192,
                        b, y0, cb, t + 1, wv, lane);

        const u16* Xs  = smem + cur * 4096;
        const u16* Ws1 = smem + CW1_OFF + cur * 8192;
        const u16* Ws2 = smem + CW2_OFF + cur * 8192;

        #pragma unroll
        for (int kk = 0; kk < 2; ++kk) {
            const int ca = ((kk << 5) + (lg << 3)) ^ ((lr & 7) << 3);
            bf16x8 xs[4];
            #pragma unroll
            for (int nf = 0; nf < 4; ++nf)
                xs[nf] = *(const bf16x8*)&Xs[((nf * 16 + lr) << 6) + ca];
            bf16x8 w1f[2], w2f[2];
            #pragma unroll
            for (int mf = 0; mf < 2; ++mf) {
                w1f[mf] = *(const bf16x8*)&Ws1[((wv * 32 + mf * 16 + lr) << 6) + ca];
                w2f[mf] = *(const bf16x8*)&Ws2[((wv * 32 + mf * 16 + lr) << 6) + ca];
            }
            #pragma unroll
            for (int mf = 0; mf < 2; ++mf)
                #pragma unroll
                for (int nf = 0; nf < 4; ++nf)
                    acc1[mf][nf] = __builtin_amdgcn_mfma_f32_16x16x32_bf16(w1f[mf], xs[nf], acc1[mf][nf], 0, 0, 0);
            #pragma unroll
            for (int mf = 0; mf < 4; ++mf)
                #pragma unroll
                for (int nf = 0; nf < 2; ++nf)
                    acc2[mf][nf] = __builtin_amdgcn_mfma_f32_16x16x32_bf16(xs[mf], w2f[nf], acc2[mf][nf], 0, 0, 0);
        }
        __syncthreads();
        cur ^= 1;
    }

    const int m0 = y0 << 6;
    // conv1 epilogue: D[co][n] -> XT[b][n][co]
    #pragma unroll
    for (int mf = 0; mf < 2; ++mf)
        #pragma unroll
        for (int nf = 0; nf < 4; ++nf) {
            int cob = cb + wv * 32 + mf * 16 + lg * 4;
            int n = m0 + nf * 16 + lr;
            union { u16 h[4]; uint2 v; } pk;
            #pragma unroll
            for (int j = 0; j < 4; ++j) pk.h[j] = f2bf(fmaxf(acc1[mf][nf][j], 0.f));
            *(uint2*)&XT[((size_t)(b * NSEQ + n)) * CDIM + cob] = pk.v;
        }
    // conv2 epilogue: D[n][co] -> Vn[b][co][n]
    #pragma unroll
    for (int mf = 0; mf < 4; ++mf)
        #pragma unroll
        for (int nf = 0; nf < 2; ++nf) {
            int nb = m0 + mf * 16 + lg * 4;
            int co = cb + wv * 32 + nf * 16 + lr;
            union { u16 h[4]; uint2 v; } pk;
            #pragma unroll
            for (int j = 0; j < 4; ++j) pk.h[j] = f2bf(fmaxf(acc2[mf][nf][j], 0.f));
            *(uint2*)&Vn[((size_t)(b * CDIM + co)) * NSEQ + nb] = pk.v;
        }
}

// ---------------------------------------------------------------------------
// rownorm / maxred (no atomics, R10)
// ---------------------------------------------------------------------------
__global__ __launch_bounds__(256)
void rownorm_kernel(const u16* __restrict__ XT, float* __restrict__ rn2,
                    float* __restrict__ bmax)
{
    __shared__ float wmax[4];
    const int tid = threadIdx.x;
    const int lane = tid & 63, wv = tid >> 6;
    const int row = (blockIdx.x << 2) + wv;
    const u16* xp = &XT[(size_t)row * CDIM + (lane << 2)];
    uint2 v = *(const uint2*)xp;
    float s = 0.f;
    #pragma unroll
    for (int j = 0; j < 4; ++j) {
        unsigned hu = (j & 1) ? ((&v.x)[j >> 1] >> 16) : ((&v.x)[j >> 1] & 0xFFFFu);
        float x = __uint_as_float(hu << 16);
        s += x * x;
    }
    #pragma unroll
    for (int off = 1; off < 64; off <<= 1) s += __shfl_xor(s, off);
    if (lane == 0) {
        rn2[row] = s;
        wmax[wv] = s;
    }
    __syncthreads();
    if (tid == 0)
        bmax[blockIdx.x] = fmaxf(fmaxf(wmax[0], wmax[1]), fmaxf(wmax[2], wmax[3]));
}

__global__ __launch_bounds__(256)
void maxred_kernel(const float* __restrict__ bmax, float* __restrict__ maxrn2)
{
    __shared__ float wred[4];
    const int tid = threadIdx.x;
    const int lane = tid & 63, wv = tid >> 6;
    const int b = blockIdx.x;
    float m = 0.f;
    #pragma unroll
    for (int i = 0; i < 4; ++i)
        m = fmaxf(m, bmax[(b << 10) + (i << 8) + tid]);
    #pragma unroll
    for (int off = 1; off < 64; off <<= 1) m = fmaxf(m, __shfl_xor(m, off));
    if (lane == 0) wred[wv] = m;
    __syncthreads();
    if (tid == 0)
        maxrn2[b] = fmaxf(fmaxf(wred[0], wred[1]), fmaxf(wred[2], wred[3]));
}

// ---------------------------------------------------------------------------
// Flash attention partials (R10 structure): 2-way key split, 32x32x16 MFMA,
// static-bound softmax (Cauchy-Schwarz m_ub), double-buffered global_load_lds.
// T4-lite: barrier B2 waits lgkmcnt(0) ONLY (P visibility) — next-chunk
// staging loads stay in flight across PV; vmcnt drains at B3 (__syncthreads).
// ---------------------------------------------------------------------------
#define M_TILE 128
#define NC 64
#define NCHUNKS 32

#define KS_OFF 0        // 2 x [64 key][256 c]  (4-bit row XOR swizzle)
#define VS_OFF 32768    // 2 x [256 c][64 n]    (3-bit row XOR swizzle)
#define P_OFF  65536    // [128 q][64 key]      (3-bit row XOR swizzle)

__device__ __forceinline__ void stage_chunk(const u16* __restrict__ XT, const u16* __restrict__ Vn,
                                            u16* Kb, u16* Vb, int b, int n0, int wv, int lane)
{
    #pragma unroll
    for (int i = 0; i < 4; ++i) {
        int f = ((i << 3) + wv) << 6;
        int fl = f + lane;
        int r = fl >> 5;
        int gsw = (fl & 31) ^ (r & 15);
        gload_lds16(&XT[(size_t)(b * NSEQ + n0 + r) * CDIM + (gsw << 3)], Kb + (f << 3));
    }
    #pragma unroll
    for (int i = 0; i < 4; ++i) {
        int f = ((i << 3) + wv) << 6;
        int fl = f + lane;
        int r = fl >> 3;
        int gsw = (fl & 7) ^ (r & 7);
        gload_lds16(&Vn[(size_t)(b * CDIM + r) * NSEQ + n0 + (gsw << 3)], Vb + (f << 3));
    }
}

__global__ __launch_bounds__(512, 2)
void attn_part_kernel(const u16* __restrict__ XT, const u16* __restrict__ Vn,
                      const float* __restrict__ rn2, const float* __restrict__ maxrn2,
                      float* __restrict__ o0, u16* __restrict__ o1,
                      float* __restrict__ lsum)
{
    __shared__ alignas(16) u16 smem[73728];     // 147.5 KB
    u16* Ps = smem + P_OFF;

    const int tid = threadIdx.x;
    const int lane = tid & 63;
    const int wv = tid >> 6;
    const int l31 = lane & 31;
    const int hi = lane >> 5;
    const int bh = blockIdx.x;                  // b*2+h
    const int b = bh >> 1, h = bh & 1;
    const int m0 = blockIdx.y * M_TILE;
    const int nbase = h * (NSEQ / 2);

    const int qt = wv & 3;
    const int kh = wv >> 2;
    const int qa = qt * 32 + l31;
    const int qsel = wv & 1;
    const int csel = wv >> 1;

    const float mq = sqrtf(rn2[(size_t)b * NSEQ + m0 + qa]) * sqrtf(maxrn2[b]);

    bf16x8 qreg[16];
    {
        const u16* qrow = &XT[(size_t)(b * NSEQ + m0 + qa) * CDIM + (hi << 3)];
        #pragma unroll
        for (int ks = 0; ks < 16; ++ks)
            qreg[ks] = *(const bf16x8*)(qrow + (ks << 4));
    }

    f32x16 o[2][2] = {};
    float lrun = 0.f;

    stage_chunk(XT, Vn, smem + KS_OFF, smem + VS_OFF, b, nbase, wv, lane);
    __syncthreads();

    int cur = 0;
    for (int ci = 0; ci < NCHUNKS; ++ci) {
        if (ci + 1 < NCHUNKS)
            stage_chunk(XT, Vn, smem + KS_OFF + (cur ^ 1) * 16384,
                        smem + VS_OFF + (cur ^ 1) * 16384,
                        b, nbase + (ci + 1) * NC, wv, lane);

        const u16* Kc = smem + KS_OFF + cur * 16384;
        const u16* Vc = smem + VS_OFF + cur * 16384;

        // ---- QK^T ----
        f32x16 s = {};
        {
            const int krow = kh * 32 + l31;
            const u16* kbase = &Kc[krow << 8];
            const int ksw = krow & 15;
            #pragma unroll
            for (int ks = 0; ks < 16; ++ks) {
                bf16x8 ka = *(const bf16x8*)&kbase[(((ks << 1) + hi) ^ ksw) << 3];
                s = __builtin_amdgcn_mfma_f32_32x32x16_bf16(ka, qreg[ks], s, 0, 0, 0);
            }
        }

        // ---- p = exp(s - m_ub) ----
        float p[16];
        float ps = 0.f;
        #pragma unroll
        for (int r = 0; r < 16; ++r) { p[r] = __expf(s[r] - mq); ps += p[r]; }
        ps += __shfl_xor(ps, 32);
        lrun += ps;

        // ---- P -> LDS ----
        {
            const int swz = qa & 7;
            #pragma unroll
            for (int r4 = 0; r4 < 4; ++r4) {
                union { u16 h4[4]; uint2 v; } pk;
                pk.h4[0] = f2bf(p[r4 * 4 + 0]); pk.h4[1] = f2bf(p[r4 * 4 + 1]);
                pk.h4[2] = f2bf(p[r4 * 4 + 2]); pk.h4[3] = f2bf(p[r4 * 4 + 3]);
                int g = (kh << 2) + r4;
                *(uint2*)&Ps[(qa << 6) + (((g ^ swz) << 3) | (hi << 2))] = pk.v;
            }
        }
        // B2 (T4-lite): P visible via lgkmcnt only; staging vmcnt stays in flight
        asm volatile("s_waitcnt lgkmcnt(0)" ::: "memory");
        __builtin_amdgcn_s_barrier();
        __builtin_amdgcn_sched_barrier(0);

        // ---- PV ----
        {
            const int q0 = ((qsel << 1) + 0) * 32 + l31;
            const int q1 = ((qsel << 1) + 1) * 32 + l31;
            const int c0 = ((csel << 1) + 0) * 32 + l31;
            const int c1 = ((csel << 1) + 1) * 32 + l31;
            #pragma unroll
            for (int ks = 0; ks < 4; ++ks) {
                const int gp = (ks << 1) + hi;
                bf16x8 pb0 = *(const bf16x8*)&Ps[(q0 << 6) + ((gp ^ (q0 & 7)) << 3)];
                bf16x8 pb1 = *(const bf16x8*)&Ps[(q1 << 6) + ((gp ^ (q1 & 7)) << 3)];
                bf16x8 va0 = *(const bf16x8*)&Vc[(c0 << 6) + ((gp ^ (c0 & 7)) << 3)];
                bf16x8 va1 = *(const bf16x8*)&Vc[(c1 << 6) + ((gp ^ (c1 & 7)) << 3)];
                o[0][0] = __builtin_amdgcn_mfma_f32_32x32x16_bf16(va0, pb0, o[0][0], 0, 0, 0);
                o[0][1] = __builtin_amdgcn_mfma_f32_32x32x16_bf16(va1, pb0, o[0][1], 0, 0, 0);
                o[1][0] = __builtin_amdgcn_mfma_f32_32x32x16_bf16(va0, pb1, o[1][0], 0, 0, 0);
                o[1][1] = __builtin_amdgcn_mfma_f32_32x32x16_bf16(va1, pb1, o[1][1], 0, 0, 0);
            }
        }

        __syncthreads();    // B3: full drain — buffers swappable, staging landed
        cur ^= 1;
    }

    if (lane < 32)
        lsum[(size_t)(((h * 2 + kh) * 4 + b)) * NSEQ + m0 + qa] = lrun;

    #pragma unroll
    for (int qi = 0; qi < 2; ++qi) {
        const int q = m0 + ((qsel << 1) + qi) * 32 + l31;
        #pragma unroll
        for (int cj = 0; cj < 2; ++cj) {
            #pragma unroll
            for (int reg = 0; reg < 16; ++reg) {
                int c = ((csel << 1) + cj) * 32 + (reg & 3) + ((reg >> 2) << 3) + (hi << 2);
                size_t oi = ((size_t)(b * CDIM + c)) * NSEQ + q;
                if (h == 0) o0[oi] = o[qi][cj][reg];
                else        o1[oi] = f2bf(o[qi][cj][reg]);
            }
        }
    }
}

// ---------------------------------------------------------------------------
// merge: out[i] = g * (O0[i] + O1[i]) / (l00+l01+l10+l11) + ref[i]
// ---------------------------------------------------------------------------
__global__ __launch_bounds__(256)
void merge_kernel(float* __restrict__ out, const u16* __restrict__ o1,
                  const float* __restrict__ lsum, const float* __restrict__ ref,
                  const float* __restrict__ gptr)
{
    const int f = (blockIdx.x << 8) + threadIdx.x;
    const int n4 = f & 1023;
    const int c = (f >> 10) & 255;
    const int b = f >> 18;
    const float g = gptr[0];

    float4 p0 = ((const float4*)out)[f];
    uint2 q1 = *(const uint2*)&o1[((size_t)(b * CDIM + c)) * NSEQ + (n4 << 2)];
    float4 rf = ((const float4*)ref)[f];

    float res[4];
    #pragma unroll
    for (int j = 0; j < 4; ++j) {
        int row = (n4 << 2) + j;
        float l = lsum[(size_t)(0 * 4 + b) * NSEQ + row]
                + lsum[(size_t)(1 * 4 + b) * NSEQ + row]
                + lsum[(size_t)(2 * 4 + b) * NSEQ + row]
                + lsum[(size_t)(3 * 4 + b) * NSEQ + row];
        float rl = 1.0f / l;
        float v0 = ((const float*)&p0)[j];
        unsigned hu = ((j & 1) ? ((&q1.x)[j >> 1] >> 16) : ((&q1.x)[j >> 1] & 0xFFFFu));
        float v1 = __uint_as_float(hu << 16);
        float a = (v0 + v1) * rl;
        res[j] = g * a + ((const float*)&rf)[j];
    }
    ((float4*)out)[f] = *(float4*)res;
}

// ---------------------------------------------------------------------------
extern "C" void kernel_launch(void* const* d_in, const int* in_sizes, int n_in,
                              void* d_out, int out_size, void* d_ws, size_t ws_size,
                              hipStream_t stream)
{
    // dict order: inputs, ref, w1, w2, gamma (dead conv on `inputs` skipped)
    const float* ref = (const float*)d_in[1];
    const float* w1  = (const float*)d_in[2];
    const float* w2  = (const float*)d_in[3];
    const float* gma = (const float*)d_in[4];
    float* out = (float*)d_out;

    u16* XT     = (u16*)d_ws;                          // [B][N][C] bf16 (Q=K)  8.39 MB
    u16* Vn     = XT + (size_t)4 * NSEQ * CDIM;        // [B][C][N] bf16 (V)    8.39 MB
    u16* padded = Vn + (size_t)4 * NSEQ * CDIM;        // [B][4356][256] bf16   8.9 MB (dead after convs)
    u16* wk1    = padded + (size_t)4 * PPIX * CDIM;    // 1.18 MB (dead after convs)
    u16* wk2    = wk1 + (size_t)9 * 65536;             // 1.18 MB (dead after convs)
    // attn-phase reuse of dead regions:
    u16*   o1     = padded;                            // [B][C][N] bf16 partial (8.39 MB)
    float* lsum   = (float*)wk1;                       // [4][B][N] f32 (0.26 MB)
    float* rn2    = (float*)wk2;                       // [B][N] f32 (64 KB)
    float* bmax   = rn2 + 16384;                       // [4096] f32 (16 KB)
    float* maxrn2 = bmax + 4096;                       // [4] f32

    hipMemsetAsync(padded, 0, (size_t)4 * PPIX * CDIM * sizeof(u16), stream);
    pad_transpose_kernel<<<dim3(64, 4, 4), 256, 0, stream>>>(ref, padded);
    w_prepack2_kernel<<<dim3(512), 256, 0, stream>>>(w1, w2, wk1, wk2);

    conv_dual_kernel<<<dim3(2, 64, 4), 256, 0, stream>>>(padded, wk1, wk2, XT, Vn);

    rownorm_kernel<<<dim3(4096), 256, 0, stream>>>(XT, rn2, bmax);        // no atomics
    maxred_kernel<<<dim3(4), 256, 0, stream>>>(bmax, maxrn2);

    attn_part_kernel<<<dim3(8, NSEQ / M_TILE), 512, 0, stream>>>(XT, Vn, rn2, maxrn2, out, o1, lsum);
    merge_kernel<<<dim3((4 * CDIM * NSEQ / 4) / 256), 256, 0, stream>>>(out, o1, lsum, ref, gma);
}

// Round 16
// 155.766 us; speedup vs baseline: 1.8350x; 1.0137x over previous
//
#include <hip/hip_runtime.h>
#include <math.h>

#define CDIM 256
#define NSEQ 4096
#define HWDIM 64
#define PPIX 4356   // 66*66 padded pixels

typedef unsigned short u16;
typedef __attribute__((ext_vector_type(8))) short bf16x8;
typedef __attribute__((ext_vector_type(4))) float f32x4;
typedef __attribute__((ext_vector_type(16))) float f32x16;

__device__ __forceinline__ u16 f2bf(float f) {
    unsigned u = __float_as_uint(f);
    unsigned r = (u + 0x7FFFu + ((u >> 16) & 1u)) >> 16;   // RN-even
    return (u16)r;
}

// async global->LDS, 16B per lane; LDS dest = wave-uniform base + lane*16
__device__ __forceinline__ void gload_lds16(const u16* g, u16* l) {
    __builtin_amdgcn_global_load_lds(
        (const __attribute__((address_space(1))) unsigned int*)g,
        (__attribute__((address_space(3))) unsigned int*)l, 16, 0, 0);
}

// ---------------------------------------------------------------------------
// pad+transpose: ref fp32 NCHW -> padded bf16 [b][pp][c], pp=(y+1)*66+(x+1)
// ---------------------------------------------------------------------------
__global__ __launch_bounds__(256)
void pad_transpose_kernel(const float* __restrict__ x, u16* __restrict__ padded)
{
    __shared__ float lds[64 * 65];
    const int tid = threadIdx.x;
    const int y = blockIdx.x, c0 = blockIdx.y << 6, b = blockIdx.z;
    #pragma unroll
    for (int i = 0; i < 16; ++i) {
        int f = tid + (i << 8);
        int c = f >> 6, xx = f & 63;
        lds[c * 65 + xx] = x[(((size_t)(b * CDIM + c0 + c)) * HWDIM + y) * HWDIM + xx];
    }
    __syncthreads();
    #pragma unroll
    for (int i = 0; i < 2; ++i) {
        int f = tid + (i << 8);
        int xx = f >> 3, c8 = f & 7;
        union { u16 h[8]; float4 v; } pk;
        #pragma unroll
        for (int j = 0; j < 8; ++j) pk.h[j] = f2bf(lds[(c8 * 8 + j) * 65 + xx]);
        *(float4*)&padded[((size_t)b * PPIX + (y + 1) * 66 + (xx + 1)) * CDIM + c0 + (c8 << 3)] = pk.v;
    }
}

// ---------------------------------------------------------------------------
// weight prepack (both): w fp32 [co][ci][3][3] -> wk bf16 [kyx][co][ci]
// ---------------------------------------------------------------------------
__global__ __launch_bounds__(256)
void w_prepack2_kernel(const float* __restrict__ w1, const float* __restrict__ w2,
                       u16* __restrict__ wk1, u16* __restrict__ wk2)
{
    int g = (blockIdx.x << 8) + threadIdx.x;     // 0..131071
    int t = g & 65535;
    const float* wp = (g < 65536 ? w1 : w2) + (size_t)t * 9;
    u16* wk = (g < 65536 ? wk1 : wk2);
    #pragma unroll
    for (int j = 0; j < 9; ++j) wk[j * 65536 + t] = f2bf(wp[j]);
}

// ---------------------------------------------------------------------------
// FUSED dual conv3x3+ReLU as 9 offset-GEMMs, double-buffered global_load_lds.
// ---------------------------------------------------------------------------
#define CW1_OFF 8192
#define CW2_OFF 24576

__device__ __forceinline__ void conv_stage2(const u16* __restrict__ padded,
                                            const u16* __restrict__ wk1,
                                            const u16* __restrict__ wk2,
                                            u16* Xb, u16* W1b, u16* W2b,
                                            int b, int y0, int cb, int t,
                                            int wv, int lane)
{
    const int kyx = t >> 2, cib = (t & 3) << 6;
    const int ky = kyx / 3, kx = kyx - ky * 3;
    #pragma unroll
    for (int i = 0; i < 2; ++i) {
        int f = ((i << 2) + wv) << 6;
        int fl = f + lane;
        int r = fl >> 3;
        int gsw = (fl & 7) ^ (r & 7);
        gload_lds16(&padded[((size_t)b * PPIX + (y0 + ky) * 66 + r + kx) * CDIM + cib + (gsw << 3)],
                    Xb + (f << 3));
    }
    #pragma unroll
    for (int i = 0; i < 4; ++i) {
        int f = ((i << 2) + wv) << 6;
        int fl = f + lane;
        int r = fl >> 3;
        int gsw = (fl & 7) ^ (r & 7);
        gload_lds16(&wk1[((size_t)kyx << 16) + (size_t)(cb + r) * 256 + cib + (gsw << 3)],
                    W1b + (f << 3));
    }
    #pragma unroll
    for (int i = 0; i < 4; ++i) {
        int f = ((i << 2) + wv) << 6;
        int fl = f + lane;
        int r = fl >> 3;
        int gsw = (fl & 7) ^ (r & 7);
        gload_lds16(&wk2[((size_t)kyx << 16) + (size_t)(cb + r) * 256 + cib + (gsw << 3)],
                    W2b + (f << 3));
    }
}

__global__ __launch_bounds__(256)
void conv_dual_kernel(const u16* __restrict__ padded,
                      const u16* __restrict__ wk1, const u16* __restrict__ wk2,
                      u16* __restrict__ XT, u16* __restrict__ Vn)
{
    __shared__ alignas(16) u16 smem[40960];    // 80 KB

    const int tid = threadIdx.x;
    const int lane = tid & 63, wv = tid >> 6;
    const int lr = lane & 15, lg = lane >> 4;
    const int cb = blockIdx.x << 7;
    const int y0 = blockIdx.y;
    const int b = blockIdx.z;

    f32x4 acc1[2][4] = {};   // conv1: D[co][n]
    f32x4 acc2[4][2] = {};   // conv2: D[n][co]

    conv_stage2(padded, wk1, wk2, smem, smem + CW1_OFF, smem + CW2_OFF,
                b, y0, cb, 0, wv, lane);
    __syncthreads();

    int cur = 0;
    for (int t = 0; t < 36; ++t) {
        if (t + 1 < 36)
            conv_stage2(padded, wk1, wk2, smem + (cur ^ 1) * 4096,
                        smem + CW1_OFF + (cur ^ 1) * 8192,
                        smem + CW2_OFF + (cur ^ 1) * 8192,
                        b, y0, cb, t + 1, wv, lane);

        const u16* Xs  = smem + cur * 4096;
        const u16* Ws1 = smem + CW1_OFF + cur * 8192;
        const u16* Ws2 = smem + CW2_OFF + cur * 8192;

        #pragma unroll
        for (int kk = 0; kk < 2; ++kk) {
            const int ca = ((kk << 5) + (lg << 3)) ^ ((lr & 7) << 3);
            bf16x8 xs[4];
            #pragma unroll
            for (int nf = 0; nf < 4; ++nf)
                xs[nf] = *(const bf16x8*)&Xs[((nf * 16 + lr) << 6) + ca];
            bf16x8 w1f[2], w2f[2];
            #pragma unroll
            for (int mf = 0; mf < 2; ++mf) {
                w1f[mf] = *(const bf16x8*)&Ws1[((wv * 32 + mf * 16 + lr) << 6) + ca];
                w2f[mf] = *(const bf16x8*)&Ws2[((wv * 32 + mf * 16 + lr) << 6) + ca];
            }
            #pragma unroll
            for (int mf = 0; mf < 2; ++mf)
                #pragma unroll
                for (int nf = 0; nf < 4; ++nf)
                    acc1[mf][nf] = __builtin_amdgcn_mfma_f32_16x16x32_bf16(w1f[mf], xs[nf], acc1[mf][nf], 0, 0, 0);
            #pragma unroll
            for (int mf = 0; mf < 4; ++mf)
                #pragma unroll
                for (int nf = 0; nf < 2; ++nf)
                    acc2[mf][nf] = __builtin_amdgcn_mfma_f32_16x16x32_bf16(xs[mf], w2f[nf], acc2[mf][nf], 0, 0, 0);
        }
        __syncthreads();
        cur ^= 1;
    }

    const int m0 = y0 << 6;
    #pragma unroll
    for (int mf = 0; mf < 2; ++mf)
        #pragma unroll
        for (int nf = 0; nf < 4; ++nf) {
            int cob = cb + wv * 32 + mf * 16 + lg * 4;
            int n = m0 + nf * 16 + lr;
            union { u16 h[4]; uint2 v; } pk;
            #pragma unroll
            for (int j = 0; j < 4; ++j) pk.h[j] = f2bf(fmaxf(acc1[mf][nf][j], 0.f));
            *(uint2*)&XT[((size_t)(b * NSEQ + n)) * CDIM + cob] = pk.v;
        }
    #pragma unroll
    for (int mf = 0; mf < 4; ++mf)
        #pragma unroll
        for (int nf = 0; nf < 2; ++nf) {
            int nb = m0 + mf * 16 + lg * 4;
            int co = cb + wv * 32 + nf * 16 + lr;
            union { u16 h[4]; uint2 v; } pk;
            #pragma unroll
            for (int j = 0; j < 4; ++j) pk.h[j] = f2bf(fmaxf(acc2[mf][nf][j], 0.f));
            *(uint2*)&Vn[((size_t)(b * CDIM + co)) * NSEQ + nb] = pk.v;
        }
}

// ---------------------------------------------------------------------------
// rownorm / maxred (no atomics)
// ---------------------------------------------------------------------------
__global__ __launch_bounds__(256)
void rownorm_kernel(const u16* __restrict__ XT, float* __restrict__ rn2,
                    float* __restrict__ bmax)
{
    __shared__ float wmax[4];
    const int tid = threadIdx.x;
    const int lane = tid & 63, wv = tid >> 6;
    const int row = (blockIdx.x << 2) + wv;
    const u16* xp = &XT[(size_t)row * CDIM + (lane << 2)];
    uint2 v = *(const uint2*)xp;
    float s = 0.f;
    #pragma unroll
    for (int j = 0; j < 4; ++j) {
        unsigned hu = (j & 1) ? ((&v.x)[j >> 1] >> 16) : ((&v.x)[j >> 1] & 0xFFFFu);
        float x = __uint_as_float(hu << 16);
        s += x * x;
    }
    #pragma unroll
    for (int off = 1; off < 64; off <<= 1) s += __shfl_xor(s, off);
    if (lane == 0) {
        rn2[row] = s;
        wmax[wv] = s;
    }
    __syncthreads();
    if (tid == 0)
        bmax[blockIdx.x] = fmaxf(fmaxf(wmax[0], wmax[1]), fmaxf(wmax[2], wmax[3]));
}

__global__ __launch_bounds__(256)
void maxred_kernel(const float* __restrict__ bmax, float* __restrict__ maxrn2)
{
    __shared__ float wred[4];
    const int tid = threadIdx.x;
    const int lane = tid & 63, wv = tid >> 6;
    const int b = blockIdx.x;
    float m = 0.f;
    #pragma unroll
    for (int i = 0; i < 4; ++i)
        m = fmaxf(m, bmax[(b << 10) + (i << 8) + tid]);
    #pragma unroll
    for (int off = 1; off < 64; off <<= 1) m = fmaxf(m, __shfl_xor(m, off));
    if (lane == 0) wred[wv] = m;
    __syncthreads();
    if (tid == 0)
        maxrn2[b] = fmaxf(fmaxf(wred[0], wred[1]), fmaxf(wred[2], wred[3]));
}

// ---------------------------------------------------------------------------
// Flash attention partials — PRODUCER/CONSUMER WAVE SPECIALIZATION.
// 1024 thr (16 waves, 1 block/CU, 4 waves/SIMD): waves 0-7 = QK producers
// (hold Q in regs, no O), waves 8-15 = PV consumers (hold O, no Q) ->
// per-wave register union ~110 <= 128. Static-bound softmax (Cauchy-Schwarz)
// keeps the classes fully decoupled (no max exchange; scale cancels).
// Window w: QK(w) || PV(w-1); K/V/P all double-buffered; ONE barrier/window.
// K staged one-ahead by QK waves; V staged same-window (lag-1) by PV waves.
// LDS = 2x32K (K) + 2x32K (V) + 2x16K (P) = 160 KB. All fragment addressing
// identical to the verified R10 kernel.
// ---------------------------------------------------------------------------
#define M_TILE 128
#define NC 64
#define NCHUNKS 32

#define VS_OFF 32768    // u16 units
#define P_OFF  65536

__device__ __forceinline__ void stage_K(const u16* __restrict__ XT, u16* Kb,
                                        int b, int n0, int wv, int lane)
{
    #pragma unroll
    for (int i = 0; i < 4; ++i) {
        int f = ((i << 3) + wv) << 6;          // wv in 0..7
        int fl = f + lane;
        int r = fl >> 5;                        // key row 0..63
        int gsw = (fl & 31) ^ (r & 15);         // 4-bit pre-swizzle
        gload_lds16(&XT[(size_t)(b * NSEQ + n0 + r) * CDIM + (gsw << 3)], Kb + (f << 3));
    }
}

__device__ __forceinline__ void stage_V(const u16* __restrict__ Vn, u16* Vb,
                                        int b, int n0, int wv, int lane)
{
    #pragma unroll
    for (int i = 0; i < 4; ++i) {
        int f = ((i << 3) + wv) << 6;          // wv in 0..7
        int fl = f + lane;
        int r = fl >> 3;                        // channel row 0..255
        int gsw = (fl & 7) ^ (r & 7);           // 3-bit pre-swizzle
        gload_lds16(&Vn[(size_t)(b * CDIM + r) * NSEQ + n0 + (gsw << 3)], Vb + (f << 3));
    }
}

__global__ __launch_bounds__(1024, 4)
void attn_part_kernel(const u16* __restrict__ XT, const u16* __restrict__ Vn,
                      const float* __restrict__ rn2, const float* __restrict__ maxrn2,
                      float* __restrict__ o0, u16* __restrict__ o1,
                      float* __restrict__ lsum)
{
    __shared__ alignas(16) u16 smem[81920];     // 160 KB exactly

    const int tid = threadIdx.x;
    const int lane = tid & 63;
    const int wid = tid >> 6;                   // 0..15
    const int l31 = lane & 31;
    const int hi = lane >> 5;
    const int bh = blockIdx.x;                  // b*2+h
    const int b = bh >> 1, h = bh & 1;
    const int m0 = blockIdx.y * M_TILE;
    const int nbase = h * (NSEQ / 2);

    if (wid < 8) {
        // ================= QK producer waves =================
        const int qt = wid & 3;                 // q-tile (32 q)
        const int kh = wid >> 2;                // key half (32 keys)
        const int qa = qt * 32 + l31;           // block-local query

        const float mq = sqrtf(rn2[(size_t)b * NSEQ + m0 + qa]) * sqrtf(maxrn2[b]);

        bf16x8 qreg[16];
        {
            const u16* qrow = &XT[(size_t)(b * NSEQ + m0 + qa) * CDIM + (hi << 3)];
            #pragma unroll
            for (int ks = 0; ks < 16; ++ks)
                qreg[ks] = *(const bf16x8*)(qrow + (ks << 4));
        }
        float lrun = 0.f;

        stage_K(XT, smem, b, nbase, wid, lane);        // K[0] -> buf 0
        __syncthreads();                               // B_pre

        for (int w = 0; w <= NCHUNKS; ++w) {
            if (w < NCHUNKS) {
                if (w + 1 < NCHUNKS)
                    stage_K(XT, smem + ((w + 1) & 1) * 16384,
                            b, nbase + (w + 1) * NC, wid, lane);

                const u16* Kc = smem + (w & 1) * 16384;
                u16* Pw = smem + P_OFF + (w & 1) * 8192;

                // ---- QK^T: s = D[key][q] ----
                f32x16 s = {};
                {
                    const int krow = kh * 32 + l31;
                    const u16* kbase = &Kc[krow << 8];
                    const int ksw = krow & 15;
                    #pragma unroll
                    for (int ks = 0; ks < 16; ++ks) {
                        bf16x8 ka = *(const bf16x8*)&kbase[(((ks << 1) + hi) ^ ksw) << 3];
                        s = __builtin_amdgcn_mfma_f32_32x32x16_bf16(ka, qreg[ks], s, 0, 0, 0);
                    }
                }

                // ---- p = exp(s - m_ub), own-half denominator ----
                float p[16];
                float ps = 0.f;
                #pragma unroll
                for (int r = 0; r < 16; ++r) { p[r] = __expf(s[r] - mq); ps += p[r]; }
                ps += __shfl_xor(ps, 32);
                lrun += ps;

                // ---- P -> LDS [q][key^swz], packed b64 writes ----
                const int swz = qa & 7;
                #pragma unroll
                for (int r4 = 0; r4 < 4; ++r4) {
                    union { u16 h4[4]; uint2 v; } pk;
                    pk.h4[0] = f2bf(p[r4 * 4 + 0]); pk.h4[1] = f2bf(p[r4 * 4 + 1]);
                    pk.h4[2] = f2bf(p[r4 * 4 + 2]); pk.h4[3] = f2bf(p[r4 * 4 + 3]);
                    int g = (kh << 2) + r4;
                    *(uint2*)&Pw[(qa << 6) + (((g ^ swz) << 3) | (hi << 2))] = pk.v;
                }
            }
            __syncthreads();                    // B(w)
        }

        if (lane < 32)
            lsum[(size_t)(((h * 2 + kh) * 4 + b)) * NSEQ + m0 + qa] = lrun;
    } else {
        // ================= PV consumer waves =================
        const int pvw = wid - 8;                // 0..7
        const int qsel = pvw & 1;               // q-tile pair
        const int csel = pvw >> 1;              // c-tile pair (0..3)

        f32x16 o[2][2] = {};

        __syncthreads();                        // B_pre (match)

        for (int w = 0; w <= NCHUNKS; ++w) {
            if (w < NCHUNKS)
                stage_V(Vn, smem + VS_OFF + (w & 1) * 16384,
                        b, nbase + w * NC, pvw, lane);
            if (w >= 1) {
                const u16* Vc = smem + VS_OFF + ((w - 1) & 1) * 16384;
                const u16* Pc = smem + P_OFF + ((w - 1) & 1) * 8192;

                const int q0 = ((qsel << 1) + 0) * 32 + l31;
                const int q1 = ((qsel << 1) + 1) * 32 + l31;
                const int c0 = ((csel << 1) + 0) * 32 + l31;
                const int c1 = ((csel << 1) + 1) * 32 + l31;
                #pragma unroll
                for (int ks = 0; ks < 4; ++ks) {
                    const int gp = (ks << 1) + hi;
                    bf16x8 pb0 = *(const bf16x8*)&Pc[(q0 << 6) + ((gp ^ (q0 & 7)) << 3)];
                    bf16x8 pb1 = *(const bf16x8*)&Pc[(q1 << 6) + ((gp ^ (q1 & 7)) << 3)];
                    bf16x8 va0 = *(const bf16x8*)&Vc[(c0 << 6) + ((gp ^ (c0 & 7)) << 3)];
                    bf16x8 va1 = *(const bf16x8*)&Vc[(c1 << 6) + ((gp ^ (c1 & 7)) << 3)];
                    o[0][0] = __builtin_amdgcn_mfma_f32_32x32x16_bf16(va0, pb0, o[0][0], 0, 0, 0);
                    o[0][1] = __builtin_amdgcn_mfma_f32_32x32x16_bf16(va1, pb0, o[0][1], 0, 0, 0);
                    o[1][0] = __builtin_amdgcn_mfma_f32_32x32x16_bf16(va0, pb1, o[1][0], 0, 0, 0);
                    o[1][1] = __builtin_amdgcn_mfma_f32_32x32x16_bf16(va1, pb1, o[1][1], 0, 0, 0);
                }
            }
            __syncthreads();                    // B(w)
        }

        // ---- partial store: D[c][q] frags -> [b][c][m] directly ----
        #pragma unroll
        for (int qi = 0; qi < 2; ++qi) {
            const int q = m0 + ((qsel << 1) + qi) * 32 + l31;
            #pragma unroll
            for (int cj = 0; cj < 2; ++cj) {
                #pragma unroll
                for (int reg = 0; reg < 16; ++reg) {
                    int c = ((csel << 1) + cj) * 32 + (reg & 3) + ((reg >> 2) << 3) + (hi << 2);
                    size_t oi = ((size_t)(b * CDIM + c)) * NSEQ + q;
                    if (h == 0) o0[oi] = o[qi][cj][reg];
                    else        o1[oi] = f2bf(o[qi][cj][reg]);
                }
            }
        }
    }
}

// ---------------------------------------------------------------------------
// merge: out[i] = g * (O0[i] + O1[i]) / (l00+l01+l10+l11) + ref[i]
// ---------------------------------------------------------------------------
__global__ __launch_bounds__(256)
void merge_kernel(float* __restrict__ out, const u16* __restrict__ o1,
                  const float* __restrict__ lsum, const float* __restrict__ ref,
                  const float* __restrict__ gptr)
{
    const int f = (blockIdx.x << 8) + threadIdx.x;
    const int n4 = f & 1023;
    const int c = (f >> 10) & 255;
    const int b = f >> 18;
    const float g = gptr[0];

    float4 p0 = ((const float4*)out)[f];
    uint2 q1 = *(const uint2*)&o1[((size_t)(b * CDIM + c)) * NSEQ + (n4 << 2)];
    float4 rf = ((const float4*)ref)[f];

    float res[4];
    #pragma unroll
    for (int j = 0; j < 4; ++j) {
        int row = (n4 << 2) + j;
        float l = lsum[(size_t)(0 * 4 + b) * NSEQ + row]
                + lsum[(size_t)(1 * 4 + b) * NSEQ + row]
                + lsum[(size_t)(2 * 4 + b) * NSEQ + row]
                + lsum[(size_t)(3 * 4 + b) * NSEQ + row];
        float rl = 1.0f / l;
        float v0 = ((const float*)&p0)[j];
        unsigned hu = ((j & 1) ? ((&q1.x)[j >> 1] >> 16) : ((&q1.x)[j >> 1] & 0xFFFFu));
        float v1 = __uint_as_float(hu << 16);
        float a = (v0 + v1) * rl;
        res[j] = g * a + ((const float*)&rf)[j];
    }
    ((float4*)out)[f] = *(float4*)res;
}

// ---------------------------------------------------------------------------
extern "C" void kernel_launch(void* const* d_in, const int* in_sizes, int n_in,
                              void* d_out, int out_size, void* d_ws, size_t ws_size,
                              hipStream_t stream)
{
    // dict order: inputs, ref, w1, w2, gamma (dead conv on `inputs` skipped)
    const float* ref = (const float*)d_in[1];
    const float* w1  = (const float*)d_in[2];
    const float* w2  = (const float*)d_in[3];
    const float* gma = (const float*)d_in[4];
    float* out = (float*)d_out;

    u16* XT     = (u16*)d_ws;                          // [B][N][C] bf16 (Q=K)  8.39 MB
    u16* Vn     = XT + (size_t)4 * NSEQ * CDIM;        // [B][C][N] bf16 (V)    8.39 MB
    u16* padded = Vn + (size_t)4 * NSEQ * CDIM;        // [B][4356][256] bf16   8.9 MB (dead after convs)
    u16* wk1    = padded + (size_t)4 * PPIX * CDIM;    // 1.18 MB (dead after convs)
    u16* wk2    = wk1 + (size_t)9 * 65536;             // 1.18 MB (dead after convs)
    // attn-phase reuse of dead regions:
    u16*   o1     = padded;                            // [B][C][N] bf16 partial (8.39 MB)
    float* lsum   = (float*)wk1;                       // [4][B][N] f32 (0.26 MB)
    float* rn2    = (float*)wk2;                       // [B][N] f32 (64 KB)
    float* bmax   = rn2 + 16384;                       // [4096] f32 (16 KB)
    float* maxrn2 = bmax + 4096;                       // [4] f32

    hipMemsetAsync(padded, 0, (size_t)4 * PPIX * CDIM * sizeof(u16), stream);
    pad_transpose_kernel<<<dim3(64, 4, 4), 256, 0, stream>>>(ref, padded);
    w_prepack2_kernel<<<dim3(512), 256, 0, stream>>>(w1, w2, wk1, wk2);

    conv_dual_kernel<<<dim3(2, 64, 4), 256, 0, stream>>>(padded, wk1, wk2, XT, Vn);

    rownorm_kernel<<<dim3(4096), 256, 0, stream>>>(XT, rn2, bmax);        // no atomics
    maxred_kernel<<<dim3(4), 256, 0, stream>>>(bmax, maxrn2);

    attn_part_kernel<<<dim3(8, NSEQ / M_TILE), 1024, 0, stream>>>(XT, Vn, rn2, maxrn2, out, o1, lsum);
    merge_kernel<<<dim3((4 * CDIM * NSEQ / 4) / 256), 256, 0, stream>>>(out, o1, lsum, ref, gma);
}

// Round 17
// 155.287 us; speedup vs baseline: 1.8406x; 1.0031x over previous
//
#include <hip/hip_runtime.h>
#include <math.h>

#define CDIM 256
#define NSEQ 4096
#define HWDIM 64
#define PPIX 4356   // 66*66 padded pixels

typedef unsigned short u16;
typedef __attribute__((ext_vector_type(8))) short bf16x8;
typedef __attribute__((ext_vector_type(4))) float f32x4;
typedef __attribute__((ext_vector_type(16))) float f32x16;

__device__ __forceinline__ u16 f2bf(float f) {
    unsigned u = __float_as_uint(f);
    unsigned r = (u + 0x7FFFu + ((u >> 16) & 1u)) >> 16;   // RN-even
    return (u16)r;
}

// async global->LDS, 16B per lane; LDS dest = wave-uniform base + lane*16
__device__ __forceinline__ void gload_lds16(const u16* g, u16* l) {
    __builtin_amdgcn_global_load_lds(
        (const __attribute__((address_space(1))) unsigned int*)g,
        (__attribute__((address_space(3))) unsigned int*)l, 16, 0, 0);
}

// ---------------------------------------------------------------------------
// pad+transpose: ref fp32 NCHW -> padded bf16 [b][pp][c], pp=(y+1)*66+(x+1)
// ---------------------------------------------------------------------------
__global__ __launch_bounds__(256)
void pad_transpose_kernel(const float* __restrict__ x, u16* __restrict__ padded)
{
    __shared__ float lds[64 * 65];
    const int tid = threadIdx.x;
    const int y = blockIdx.x, c0 = blockIdx.y << 6, b = blockIdx.z;
    #pragma unroll
    for (int i = 0; i < 16; ++i) {
        int f = tid + (i << 8);
        int c = f >> 6, xx = f & 63;
        lds[c * 65 + xx] = x[(((size_t)(b * CDIM + c0 + c)) * HWDIM + y) * HWDIM + xx];
    }
    __syncthreads();
    #pragma unroll
    for (int i = 0; i < 2; ++i) {
        int f = tid + (i << 8);
        int xx = f >> 3, c8 = f & 7;
        union { u16 h[8]; float4 v; } pk;
        #pragma unroll
        for (int j = 0; j < 8; ++j) pk.h[j] = f2bf(lds[(c8 * 8 + j) * 65 + xx]);
        *(float4*)&padded[((size_t)b * PPIX + (y + 1) * 66 + (xx + 1)) * CDIM + c0 + (c8 << 3)] = pk.v;
    }
}

// ---------------------------------------------------------------------------
// weight prepack (both): w fp32 [co][ci][3][3] -> wk bf16 [kyx][co][ci]
// ---------------------------------------------------------------------------
__global__ __launch_bounds__(256)
void w_prepack2_kernel(const float* __restrict__ w1, const float* __restrict__ w2,
                       u16* __restrict__ wk1, u16* __restrict__ wk2)
{
    int g = (blockIdx.x << 8) + threadIdx.x;     // 0..131071
    int t = g & 65535;
    const float* wp = (g < 65536 ? w1 : w2) + (size_t)t * 9;
    u16* wk = (g < 65536 ? wk1 : wk2);
    #pragma unroll
    for (int j = 0; j < 9; ++j) wk[j * 65536 + t] = f2bf(wp[j]);
}

// ---------------------------------------------------------------------------
// FUSED dual conv3x3+ReLU as 9 offset-GEMMs, double-buffered global_load_lds.
// ---------------------------------------------------------------------------
#define CW1_OFF 8192
#define CW2_OFF 24576

__device__ __forceinline__ void conv_stage2(const u16* __restrict__ padded,
                                            const u16* __restrict__ wk1,
                                            const u16* __restrict__ wk2,
                                            u16* Xb, u16* W1b, u16* W2b,
                                            int b, int y0, int cb, int t,
                                            int wv, int lane)
{
    const int kyx = t >> 2, cib = (t & 3) << 6;
    const int ky = kyx / 3, kx = kyx - ky * 3;
    #pragma unroll
    for (int i = 0; i < 2; ++i) {
        int f = ((i << 2) + wv) << 6;
        int fl = f + lane;
        int r = fl >> 3;
        int gsw = (fl & 7) ^ (r & 7);
        gload_lds16(&padded[((size_t)b * PPIX + (y0 + ky) * 66 + r + kx) * CDIM + cib + (gsw << 3)],
                    Xb + (f << 3));
    }
    #pragma unroll
    for (int i = 0; i < 4; ++i) {
        int f = ((i << 2) + wv) << 6;
        int fl = f + lane;
        int r = fl >> 3;
        int gsw = (fl & 7) ^ (r & 7);
        gload_lds16(&wk1[((size_t)kyx << 16) + (size_t)(cb + r) * 256 + cib + (gsw << 3)],
                    W1b + (f << 3));
    }
    #pragma unroll
    for (int i = 0; i < 4; ++i) {
        int f = ((i << 2) + wv) << 6;
        int fl = f + lane;
        int r = fl >> 3;
        int gsw = (fl & 7) ^ (r & 7);
        gload_lds16(&wk2[((size_t)kyx << 16) + (size_t)(cb + r) * 256 + cib + (gsw << 3)],
                    W2b + (f << 3));
    }
}

__global__ __launch_bounds__(256)
void conv_dual_kernel(const u16* __restrict__ padded,
                      const u16* __restrict__ wk1, const u16* __restrict__ wk2,
                      u16* __restrict__ XT, u16* __restrict__ Vn)
{
    __shared__ alignas(16) u16 smem[40960];    // 80 KB

    const int tid = threadIdx.x;
    const int lane = tid & 63, wv = tid >> 6;
    const int lr = lane & 15, lg = lane >> 4;
    const int cb = blockIdx.x << 7;
    const int y0 = blockIdx.y;
    const int b = blockIdx.z;

    f32x4 acc1[2][4] = {};   // conv1: D[co][n]
    f32x4 acc2[4][2] = {};   // conv2: D[n][co]

    conv_stage2(padded, wk1, wk2, smem, smem + CW1_OFF, smem + CW2_OFF,
                b, y0, cb, 0, wv, lane);
    __syncthreads();

    int cur = 0;
    for (int t = 0; t < 36; ++t) {
        if (t + 1 < 36)
            conv_stage2(padded, wk1, wk2, smem + (cur ^ 1) * 4096,
                        smem + CW1_OFF + (cur ^ 1) * 8192,
                        smem + CW2_OFF + (cur ^ 1) * 8192,
                        b, y0, cb, t + 1, wv, lane);

        const u16* Xs  = smem + cur * 4096;
        const u16* Ws1 = smem + CW1_OFF + cur * 8192;
        const u16* Ws2 = smem + CW2_OFF + cur * 8192;

        #pragma unroll
        for (int kk = 0; kk < 2; ++kk) {
            const int ca = ((kk << 5) + (lg << 3)) ^ ((lr & 7) << 3);
            bf16x8 xs[4];
            #pragma unroll
            for (int nf = 0; nf < 4; ++nf)
                xs[nf] = *(const bf16x8*)&Xs[((nf * 16 + lr) << 6) + ca];
            bf16x8 w1f[2], w2f[2];
            #pragma unroll
            for (int mf = 0; mf < 2; ++mf) {
                w1f[mf] = *(const bf16x8*)&Ws1[((wv * 32 + mf * 16 + lr) << 6) + ca];
                w2f[mf] = *(const bf16x8*)&Ws2[((wv * 32 + mf * 16 + lr) << 6) + ca];
            }
            #pragma unroll
            for (int mf = 0; mf < 2; ++mf)
                #pragma unroll
                for (int nf = 0; nf < 4; ++nf)
                    acc1[mf][nf] = __builtin_amdgcn_mfma_f32_16x16x32_bf16(w1f[mf], xs[nf], acc1[mf][nf], 0, 0, 0);
            #pragma unroll
            for (int mf = 0; mf < 4; ++mf)
                #pragma unroll
                for (int nf = 0; nf < 2; ++nf)
                    acc2[mf][nf] = __builtin_amdgcn_mfma_f32_16x16x32_bf16(xs[mf], w2f[nf], acc2[mf][nf], 0, 0, 0);
        }
        __syncthreads();
        cur ^= 1;
    }

    const int m0 = y0 << 6;
    #pragma unroll
    for (int mf = 0; mf < 2; ++mf)
        #pragma unroll
        for (int nf = 0; nf < 4; ++nf) {
            int cob = cb + wv * 32 + mf * 16 + lg * 4;
            int n = m0 + nf * 16 + lr;
            union { u16 h[4]; uint2 v; } pk;
            #pragma unroll
            for (int j = 0; j < 4; ++j) pk.h[j] = f2bf(fmaxf(acc1[mf][nf][j], 0.f));
            *(uint2*)&XT[((size_t)(b * NSEQ + n)) * CDIM + cob] = pk.v;
        }
    #pragma unroll
    for (int mf = 0; mf < 4; ++mf)
        #pragma unroll
        for (int nf = 0; nf < 2; ++nf) {
            int nb = m0 + mf * 16 + lg * 4;
            int co = cb + wv * 32 + nf * 16 + lr;
            union { u16 h[4]; uint2 v; } pk;
            #pragma unroll
            for (int j = 0; j < 4; ++j) pk.h[j] = f2bf(fmaxf(acc2[mf][nf][j], 0.f));
            *(uint2*)&Vn[((size_t)(b * CDIM + co)) * NSEQ + nb] = pk.v;
        }
}

// ---------------------------------------------------------------------------
// rownorm / maxred (no atomics)
// ---------------------------------------------------------------------------
__global__ __launch_bounds__(256)
void rownorm_kernel(const u16* __restrict__ XT, float* __restrict__ rn2,
                    float* __restrict__ bmax)
{
    __shared__ float wmax[4];
    const int tid = threadIdx.x;
    const int lane = tid & 63, wv = tid >> 6;
    const int row = (blockIdx.x << 2) + wv;
    const u16* xp = &XT[(size_t)row * CDIM + (lane << 2)];
    uint2 v = *(const uint2*)xp;
    float s = 0.f;
    #pragma unroll
    for (int j = 0; j < 4; ++j) {
        unsigned hu = (j & 1) ? ((&v.x)[j >> 1] >> 16) : ((&v.x)[j >> 1] & 0xFFFFu);
        float x = __uint_as_float(hu << 16);
        s += x * x;
    }
    #pragma unroll
    for (int off = 1; off < 64; off <<= 1) s += __shfl_xor(s, off);
    if (lane == 0) {
        rn2[row] = s;
        wmax[wv] = s;
    }
    __syncthreads();
    if (tid == 0)
        bmax[blockIdx.x] = fmaxf(fmaxf(wmax[0], wmax[1]), fmaxf(wmax[2], wmax[3]));
}

__global__ __launch_bounds__(256)
void maxred_kernel(const float* __restrict__ bmax, float* __restrict__ maxrn2)
{
    __shared__ float wred[4];
    const int tid = threadIdx.x;
    const int lane = tid & 63, wv = tid >> 6;
    const int b = blockIdx.x;
    float m = 0.f;
    #pragma unroll
    for (int i = 0; i < 4; ++i)
        m = fmaxf(m, bmax[(b << 10) + (i << 8) + tid]);
    #pragma unroll
    for (int off = 1; off < 64; off <<= 1) m = fmaxf(m, __shfl_xor(m, off));
    if (lane == 0) wred[wv] = m;
    __syncthreads();
    if (tid == 0)
        maxrn2[b] = fmaxf(fmaxf(wred[0], wred[1]), fmaxf(wred[2], wred[3]));
}

// ---------------------------------------------------------------------------
// Flash attention partials — producer/consumer wave specialization (R16)
// with free register allocation: __launch_bounds__(1024) only (launchability
// forces <=128 unified regs/wave; arch/acc split left to the allocator) and
// QK's p[16] array fused into per-4 exp->pack->store (live range 16 -> 4).
// ---------------------------------------------------------------------------
#define M_TILE 128
#define NC 64
#define NCHUNKS 32

#define VS_OFF 32768    // u16 units
#define P_OFF  65536

__device__ __forceinline__ void stage_K(const u16* __restrict__ XT, u16* Kb,
                                        int b, int n0, int wv, int lane)
{
    #pragma unroll
    for (int i = 0; i < 4; ++i) {
        int f = ((i << 3) + wv) << 6;          // wv in 0..7
        int fl = f + lane;
        int r = fl >> 5;                        // key row 0..63
        int gsw = (fl & 31) ^ (r & 15);         // 4-bit pre-swizzle
        gload_lds16(&XT[(size_t)(b * NSEQ + n0 + r) * CDIM + (gsw << 3)], Kb + (f << 3));
    }
}

__device__ __forceinline__ void stage_V(const u16* __restrict__ Vn, u16* Vb,
                                        int b, int n0, int wv, int lane)
{
    #pragma unroll
    for (int i = 0; i < 4; ++i) {
        int f = ((i << 3) + wv) << 6;          // wv in 0..7
        int fl = f + lane;
        int r = fl >> 3;                        // channel row 0..255
        int gsw = (fl & 7) ^ (r & 7);           // 3-bit pre-swizzle
        gload_lds16(&Vn[(size_t)(b * CDIM + r) * NSEQ + n0 + (gsw << 3)], Vb + (f << 3));
    }
}

__global__ __launch_bounds__(1024)
void attn_part_kernel(const u16* __restrict__ XT, const u16* __restrict__ Vn,
                      const float* __restrict__ rn2, const float* __restrict__ maxrn2,
                      float* __restrict__ o0, u16* __restrict__ o1,
                      float* __restrict__ lsum)
{
    __shared__ alignas(16) u16 smem[81920];     // 160 KB exactly

    const int tid = threadIdx.x;
    const int lane = tid & 63;
    const int wid = tid >> 6;                   // 0..15
    const int l31 = lane & 31;
    const int hi = lane >> 5;
    const int bh = blockIdx.x;                  // b*2+h
    const int b = bh >> 1, h = bh & 1;
    const int m0 = blockIdx.y * M_TILE;
    const int nbase = h * (NSEQ / 2);

    if (wid < 8) {
        // ================= QK producer waves =================
        const int qt = wid & 3;                 // q-tile (32 q)
        const int kh = wid >> 2;                // key half (32 keys)
        const int qa = qt * 32 + l31;           // block-local query

        const float mq = sqrtf(rn2[(size_t)b * NSEQ + m0 + qa]) * sqrtf(maxrn2[b]);

        bf16x8 qreg[16];
        {
            const u16* qrow = &XT[(size_t)(b * NSEQ + m0 + qa) * CDIM + (hi << 3)];
            #pragma unroll
            for (int ks = 0; ks < 16; ++ks)
                qreg[ks] = *(const bf16x8*)(qrow + (ks << 4));
        }
        float lrun = 0.f;

        stage_K(XT, smem, b, nbase, wid, lane);        // K[0] -> buf 0
        __syncthreads();                               // B_pre

        for (int w = 0; w <= NCHUNKS; ++w) {
            if (w < NCHUNKS) {
                if (w + 1 < NCHUNKS)
                    stage_K(XT, smem + ((w + 1) & 1) * 16384,
                            b, nbase + (w + 1) * NC, wid, lane);

                const u16* Kc = smem + (w & 1) * 16384;
                u16* Pw = smem + P_OFF + (w & 1) * 8192;

                // ---- QK^T: s = D[key][q] ----
                f32x16 s = {};
                {
                    const int krow = kh * 32 + l31;
                    const u16* kbase = &Kc[krow << 8];
                    const int ksw = krow & 15;
                    #pragma unroll
                    for (int ks = 0; ks < 16; ++ks) {
                        bf16x8 ka = *(const bf16x8*)&kbase[(((ks << 1) + hi) ^ ksw) << 3];
                        s = __builtin_amdgcn_mfma_f32_32x32x16_bf16(ka, qreg[ks], s, 0, 0, 0);
                    }
                }

                // ---- fused exp -> pack -> P store (per 4 keys; low live range) ----
                const int swz = qa & 7;
                float ps = 0.f;
                #pragma unroll
                for (int r4 = 0; r4 < 4; ++r4) {
                    float e0 = __expf(s[r4 * 4 + 0] - mq);
                    float e1 = __expf(s[r4 * 4 + 1] - mq);
                    float e2 = __expf(s[r4 * 4 + 2] - mq);
                    float e3 = __expf(s[r4 * 4 + 3] - mq);
                    ps += (e0 + e1) + (e2 + e3);
                    union { u16 h4[4]; uint2 v; } pk;
                    pk.h4[0] = f2bf(e0); pk.h4[1] = f2bf(e1);
                    pk.h4[2] = f2bf(e2); pk.h4[3] = f2bf(e3);
                    int g = (kh << 2) + r4;
                    *(uint2*)&Pw[(qa << 6) + (((g ^ swz) << 3) | (hi << 2))] = pk.v;
                }
                ps += __shfl_xor(ps, 32);
                lrun += ps;
            }
            __syncthreads();                    // B(w)
        }

        if (lane < 32)
            lsum[(size_t)(((h * 2 + kh) * 4 + b)) * NSEQ + m0 + qa] = lrun;
    } else {
        // ================= PV consumer waves =================
        const int pvw = wid - 8;                // 0..7
        const int qsel = pvw & 1;               // q-tile pair
        const int csel = pvw >> 1;              // c-tile pair (0..3)

        f32x16 o[2][2] = {};

        __syncthreads();                        // B_pre (match)

        for (int w = 0; w <= NCHUNKS; ++w) {
            if (w < NCHUNKS)
                stage_V(Vn, smem + VS_OFF + (w & 1) * 16384,
                        b, nbase + w * NC, pvw, lane);
            if (w >= 1) {
                const u16* Vc = smem + VS_OFF + ((w - 1) & 1) * 16384;
                const u16* Pc = smem + P_OFF + ((w - 1) & 1) * 8192;

                const int q0 = ((qsel << 1) + 0) * 32 + l31;
                const int q1 = ((qsel << 1) + 1) * 32 + l31;
                const int c0 = ((csel << 1) + 0) * 32 + l31;
                const int c1 = ((csel << 1) + 1) * 32 + l31;
                #pragma unroll
                for (int ks = 0; ks < 4; ++ks) {
                    const int gp = (ks << 1) + hi;
                    bf16x8 pb0 = *(const bf16x8*)&Pc[(q0 << 6) + ((gp ^ (q0 & 7)) << 3)];
                    bf16x8 pb1 = *(const bf16x8*)&Pc[(q1 << 6) + ((gp ^ (q1 & 7)) << 3)];
                    bf16x8 va0 = *(const bf16x8*)&Vc[(c0 << 6) + ((gp ^ (c0 & 7)) << 3)];
                    bf16x8 va1 = *(const bf16x8*)&Vc[(c1 << 6) + ((gp ^ (c1 & 7)) << 3)];
                    o[0][0] = __builtin_amdgcn_mfma_f32_32x32x16_bf16(va0, pb0, o[0][0], 0, 0, 0);
                    o[0][1] = __builtin_amdgcn_mfma_f32_32x32x16_bf16(va1, pb0, o[0][1], 0, 0, 0);
                    o[1][0] = __builtin_amdgcn_mfma_f32_32x32x16_bf16(va0, pb1, o[1][0], 0, 0, 0);
                    o[1][1] = __builtin_amdgcn_mfma_f32_32x32x16_bf16(va1, pb1, o[1][1], 0, 0, 0);
                }
            }
            __syncthreads();                    // B(w)
        }

        // ---- partial store: D[c][q] frags -> [b][c][m] directly ----
        #pragma unroll
        for (int qi = 0; qi < 2; ++qi) {
            const int q = m0 + ((qsel << 1) + qi) * 32 + l31;
            #pragma unroll
            for (int cj = 0; cj < 2; ++cj) {
                #pragma unroll
                for (int reg = 0; reg < 16; ++reg) {
                    int c = ((csel << 1) + cj) * 32 + (reg & 3) + ((reg >> 2) << 3) + (hi << 2);
                    size_t oi = ((size_t)(b * CDIM + c)) * NSEQ + q;
                    if (h == 0) o0[oi] = o[qi][cj][reg];
                    else        o1[oi] = f2bf(o[qi][cj][reg]);
                }
            }
        }
    }
}

// ---------------------------------------------------------------------------
// merge: out[i] = g * (O0[i] + O1[i]) / (l00+l01+l10+l11) + ref[i]
// ---------------------------------------------------------------------------
__global__ __launch_bounds__(256)
void merge_kernel(float* __restrict__ out, const u16* __restrict__ o1,
                  const float* __restrict__ lsum, const float* __restrict__ ref,
                  const float* __restrict__ gptr)
{
    const int f = (blockIdx.x << 8) + threadIdx.x;
    const int n4 = f & 1023;
    const int c = (f >> 10) & 255;
    const int b = f >> 18;
    const float g = gptr[0];

    float4 p0 = ((const float4*)out)[f];
    uint2 q1 = *(const uint2*)&o1[((size_t)(b * CDIM + c)) * NSEQ + (n4 << 2)];
    float4 rf = ((const float4*)ref)[f];

    float res[4];
    #pragma unroll
    for (int j = 0; j < 4; ++j) {
        int row = (n4 << 2) + j;
        float l = lsum[(size_t)(0 * 4 + b) * NSEQ + row]
                + lsum[(size_t)(1 * 4 + b) * NSEQ + row]
                + lsum[(size_t)(2 * 4 + b) * NSEQ + row]
                + lsum[(size_t)(3 * 4 + b) * NSEQ + row];
        float rl = 1.0f / l;
        float v0 = ((const float*)&p0)[j];
        unsigned hu = ((j & 1) ? ((&q1.x)[j >> 1] >> 16) : ((&q1.x)[j >> 1] & 0xFFFFu));
        float v1 = __uint_as_float(hu << 16);
        float a = (v0 + v1) * rl;
        res[j] = g * a + ((const float*)&rf)[j];
    }
    ((float4*)out)[f] = *(float4*)res;
}

// ---------------------------------------------------------------------------
extern "C" void kernel_launch(void* const* d_in, const int* in_sizes, int n_in,
                              void* d_out, int out_size, void* d_ws, size_t ws_size,
                              hipStream_t stream)
{
    // dict order: inputs, ref, w1, w2, gamma (dead conv on `inputs` skipped)
    const float* ref = (const float*)d_in[1];
    const float* w1  = (const float*)d_in[2];
    const float* w2  = (const float*)d_in[3];
    const float* gma = (const float*)d_in[4];
    float* out = (float*)d_out;

    u16* XT     = (u16*)d_ws;                          // [B][N][C] bf16 (Q=K)  8.39 MB
    u16* Vn     = XT + (size_t)4 * NSEQ * CDIM;        // [B][C][N] bf16 (V)    8.39 MB
    u16* padded = Vn + (size_t)4 * NSEQ * CDIM;        // [B][4356][256] bf16   8.9 MB (dead after convs)
    u16* wk1    = padded + (size_t)4 * PPIX * CDIM;    // 1.18 MB (dead after convs)
    u16* wk2    = wk1 + (size_t)9 * 65536;             // 1.18 MB (dead after convs)
    // attn-phase reuse of dead regions:
    u16*   o1     = padded;                            // [B][C][N] bf16 partial (8.39 MB)
    float* lsum   = (float*)wk1;                       // [4][B][N] f32 (0.26 MB)
    float* rn2    = (float*)wk2;                       // [B][N] f32 (64 KB)
    float* bmax   = rn2 + 16384;                       // [4096] f32 (16 KB)
    float* maxrn2 = bmax + 4096;                       // [4] f32

    hipMemsetAsync(padded, 0, (size_t)4 * PPIX * CDIM * sizeof(u16), stream);
    pad_transpose_kernel<<<dim3(64, 4, 4), 256, 0, stream>>>(ref, padded);
    w_prepack2_kernel<<<dim3(512), 256, 0, stream>>>(w1, w2, wk1, wk2);

    conv_dual_kernel<<<dim3(2, 64, 4), 256, 0, stream>>>(padded, wk1, wk2, XT, Vn);

    rownorm_kernel<<<dim3(4096), 256, 0, stream>>>(XT, rn2, bmax);        // no atomics
    maxred_kernel<<<dim3(4), 256, 0, stream>>>(bmax, maxrn2);

    attn_part_kernel<<<dim3(8, NSEQ / M_TILE), 1024, 0, stream>>>(XT, Vn, rn2, maxrn2, out, o1, lsum);
    merge_kernel<<<dim3((4 * CDIM * NSEQ / 4) / 256), 256, 0, stream>>>(out, o1, lsum, ref, gma);
}

// Round 19
// 155.168 us; speedup vs baseline: 1.8420x; 1.0008x over previous
//
#include <hip/hip_runtime.h>
#include <math.h>

#define CDIM 256
#define NSEQ 4096
#define HWDIM 64
#define PPIX 4356   // 66*66 padded pixels

typedef unsigned short u16;
typedef __attribute__((ext_vector_type(8))) short bf16x8;
typedef __attribute__((ext_vector_type(4))) float f32x4;
typedef __attribute__((ext_vector_type(16))) float f32x16;

__device__ __forceinline__ u16 f2bf(float f) {
    unsigned u = __float_as_uint(f);
    unsigned r = (u + 0x7FFFu + ((u >> 16) & 1u)) >> 16;   // RN-even
    return (u16)r;
}

// async global->LDS, 16B per lane; LDS dest = wave-uniform base + lane*16
__device__ __forceinline__ void gload_lds16(const u16* g, u16* l) {
    __builtin_amdgcn_global_load_lds(
        (const __attribute__((address_space(1))) unsigned int*)g,
        (__attribute__((address_space(3))) unsigned int*)l, 16, 0, 0);
}

// ---------------------------------------------------------------------------
// pad+transpose: ref fp32 NCHW -> padded bf16 [b][pp][c], pp=(y+1)*66+(x+1)
// ---------------------------------------------------------------------------
__global__ __launch_bounds__(256)
void pad_transpose_kernel(const float* __restrict__ x, u16* __restrict__ padded)
{
    __shared__ float lds[64 * 65];
    const int tid = threadIdx.x;
    const int y = blockIdx.x, c0 = blockIdx.y << 6, b = blockIdx.z;
    #pragma unroll
    for (int i = 0; i < 16; ++i) {
        int f = tid + (i << 8);
        int c = f >> 6, xx = f & 63;
        lds[c * 65 + xx] = x[(((size_t)(b * CDIM + c0 + c)) * HWDIM + y) * HWDIM + xx];
    }
    __syncthreads();
    #pragma unroll
    for (int i = 0; i < 2; ++i) {
        int f = tid + (i << 8);
        int xx = f >> 3, c8 = f & 7;
        union { u16 h[8]; float4 v; } pk;
        #pragma unroll
        for (int j = 0; j < 8; ++j) pk.h[j] = f2bf(lds[(c8 * 8 + j) * 65 + xx]);
        *(float4*)&padded[((size_t)b * PPIX + (y + 1) * 66 + (xx + 1)) * CDIM + c0 + (c8 << 3)] = pk.v;
    }
}

// ---------------------------------------------------------------------------
// weight prepack (both): w fp32 [co][ci][3][3] -> wk bf16 [kyx][co][ci]
// ---------------------------------------------------------------------------
__global__ __launch_bounds__(256)
void w_prepack2_kernel(const float* __restrict__ w1, const float* __restrict__ w2,
                       u16* __restrict__ wk1, u16* __restrict__ wk2)
{
    int g = (blockIdx.x << 8) + threadIdx.x;     // 0..131071
    int t = g & 65535;
    const float* wp = (g < 65536 ? w1 : w2) + (size_t)t * 9;
    u16* wk = (g < 65536 ? wk1 : wk2);
    #pragma unroll
    for (int j = 0; j < 9; ++j) wk[j * 65536 + t] = f2bf(wp[j]);
}

// ---------------------------------------------------------------------------
// FUSED dual conv3x3+ReLU as 9 offset-GEMMs, double-buffered global_load_lds.
// One X staging serves both convs (Xs frags are conv1's B AND conv2's A).
// conv1 -> XT[b][n][co] (D[co][n]); conv2 -> Vn[b][co][n] (D[n][co]).
// LDS: X dbuf 2x8KB + W1 dbuf 2x16KB + W2 dbuf 2x16KB = 80 KB.
// ---------------------------------------------------------------------------
#define CW1_OFF 8192
#define CW2_OFF 24576

__device__ __forceinline__ void conv_stage2(const u16* __restrict__ padded,
                                            const u16* __restrict__ wk1,
                                            const u16* __restrict__ wk2,
                                            u16* Xb, u16* W1b, u16* W2b,
                                            int b, int y0, int cb, int t,
                                            int wv, int lane)
{
    const int kyx = t >> 2, cib = (t & 3) << 6;
    const int ky = kyx / 3, kx = kyx - ky * 3;
    #pragma unroll
    for (int i = 0; i < 2; ++i) {
        int f = ((i << 2) + wv) << 6;
        int fl = f + lane;
        int r = fl >> 3;
        int gsw = (fl & 7) ^ (r & 7);
        gload_lds16(&padded[((size_t)b * PPIX + (y0 + ky) * 66 + r + kx) * CDIM + cib + (gsw << 3)],
                    Xb + (f << 3));
    }
    #pragma unroll
    for (int i = 0; i < 4; ++i) {
        int f = ((i << 2) + wv) << 6;
        int fl = f + lane;
        int r = fl >> 3;
        int gsw = (fl & 7) ^ (r & 7);
        gload_lds16(&wk1[((size_t)kyx << 16) + (size_t)(cb + r) * 256 + cib + (gsw << 3)],
                    W1b + (f << 3));
    }
    #pragma unroll
    for (int i = 0; i < 4; ++i) {
        int f = ((i << 2) + wv) << 6;
        int fl = f + lane;
        int r = fl >> 3;
        int gsw = (fl & 7) ^ (r & 7);
        gload_lds16(&wk2[((size_t)kyx << 16) + (size_t)(cb + r) * 256 + cib + (gsw << 3)],
                    W2b + (f << 3));
    }
}

__global__ __launch_bounds__(256)
void conv_dual_kernel(const u16* __restrict__ padded,
                      const u16* __restrict__ wk1, const u16* __restrict__ wk2,
                      u16* __restrict__ XT, u16* __restrict__ Vn)
{
    __shared__ alignas(16) u16 smem[40960];    // 80 KB

    const int tid = threadIdx.x;
    const int lane = tid & 63, wv = tid >> 6;
    const int lr = lane & 15, lg = lane >> 4;
    const int cb = blockIdx.x << 7;
    const int y0 = blockIdx.y;
    const int b = blockIdx.z;

    f32x4 acc1[2][4] = {};   // conv1: D[co][n]
    f32x4 acc2[4][2] = {};   // conv2: D[n][co]

    conv_stage2(padded, wk1, wk2, smem, smem + CW1_OFF, smem + CW2_OFF,
                b, y0, cb, 0, wv, lane);
    __syncthreads();

    int cur = 0;
    for (int t = 0; t < 36; ++t) {
        if (t + 1 < 36)
            conv_stage2(padded, wk1, wk2, smem + (cur ^ 1) * 4096,
                        smem + CW1_OFF + (cur ^ 1) * 8192,
                        smem + CW2_OFF + (cur ^ 1) * 8192,
                        b, y0, cb, t + 1, wv, lane);

        const u16* Xs  = smem + cur * 4096;
        const u16* Ws1 = smem + CW1_OFF + cur * 8192;
        const u16* Ws2 = smem + CW2_OFF + cur * 8192;

        #pragma unroll
        for (int kk = 0; kk < 2; ++kk) {
            const int ca = ((kk << 5) + (lg << 3)) ^ ((lr & 7) << 3);
            bf16x8 xs[4];
            #pragma unroll
            for (int nf = 0; nf < 4; ++nf)
                xs[nf] = *(const bf16x8*)&Xs[((nf * 16 + lr) << 6) + ca];
            bf16x8 w1f[2], w2f[2];
            #pragma unroll
            for (int mf = 0; mf < 2; ++mf) {
                w1f[mf] = *(const bf16x8*)&Ws1[((wv * 32 + mf * 16 + lr) << 6) + ca];
                w2f[mf] = *(const bf16x8*)&Ws2[((wv * 32 + mf * 16 + lr) << 6) + ca];
            }
            #pragma unroll
            for (int mf = 0; mf < 2; ++mf)
                #pragma unroll
                for (int nf = 0; nf < 4; ++nf)
                    acc1[mf][nf] = __builtin_amdgcn_mfma_f32_16x16x32_bf16(w1f[mf], xs[nf], acc1[mf][nf], 0, 0, 0);
            #pragma unroll
            for (int mf = 0; mf < 4; ++mf)
                #pragma unroll
                for (int nf = 0; nf < 2; ++nf)
                    acc2[mf][nf] = __builtin_amdgcn_mfma_f32_16x16x32_bf16(xs[mf], w2f[nf], acc2[mf][nf], 0, 0, 0);
        }
        __syncthreads();
        cur ^= 1;
    }

    const int m0 = y0 << 6;
    // conv1 epilogue: D[co][n] -> XT[b][n][co]
    #pragma unroll
    for (int mf = 0; mf < 2; ++mf)
        #pragma unroll
        for (int nf = 0; nf < 4; ++nf) {
            int cob = cb + wv * 32 + mf * 16 + lg * 4;
            int n = m0 + nf * 16 + lr;
            union { u16 h[4]; uint2 v; } pk;
            #pragma unroll
            for (int j = 0; j < 4; ++j) pk.h[j] = f2bf(fmaxf(acc1[mf][nf][j], 0.f));
            *(uint2*)&XT[((size_t)(b * NSEQ + n)) * CDIM + cob] = pk.v;
        }
    // conv2 epilogue: D[n][co] -> Vn[b][co][n]
    #pragma unroll
    for (int mf = 0; mf < 4; ++mf)
        #pragma unroll
        for (int nf = 0; nf < 2; ++nf) {
            int nb = m0 + mf * 16 + lg * 4;
            int co = cb + wv * 32 + nf * 16 + lr;
            union { u16 h[4]; uint2 v; } pk;
            #pragma unroll
            for (int j = 0; j < 4; ++j) pk.h[j] = f2bf(fmaxf(acc2[mf][nf][j], 0.f));
            *(uint2*)&Vn[((size_t)(b * CDIM + co)) * NSEQ + nb] = pk.v;
        }
}

// ---------------------------------------------------------------------------
// rownorm / maxred (no atomics)
// ---------------------------------------------------------------------------
__global__ __launch_bounds__(256)
void rownorm_kernel(const u16* __restrict__ XT, float* __restrict__ rn2,
                    float* __restrict__ bmax)
{
    __shared__ float wmax[4];
    const int tid = threadIdx.x;
    const int lane = tid & 63, wv = tid >> 6;
    const int row = (blockIdx.x << 2) + wv;
    const u16* xp = &XT[(size_t)row * CDIM + (lane << 2)];
    uint2 v = *(const uint2*)xp;
    float s = 0.f;
    #pragma unroll
    for (int j = 0; j < 4; ++j) {
        unsigned hu = (j & 1) ? ((&v.x)[j >> 1] >> 16) : ((&v.x)[j >> 1] & 0xFFFFu);
        float x = __uint_as_float(hu << 16);
        s += x * x;
    }
    #pragma unroll
    for (int off = 1; off < 64; off <<= 1) s += __shfl_xor(s, off);
    if (lane == 0) {
        rn2[row] = s;
        wmax[wv] = s;
    }
    __syncthreads();
    if (tid == 0)
        bmax[blockIdx.x] = fmaxf(fmaxf(wmax[0], wmax[1]), fmaxf(wmax[2], wmax[3]));
}

__global__ __launch_bounds__(256)
void maxred_kernel(const float* __restrict__ bmax, float* __restrict__ maxrn2)
{
    __shared__ float wred[4];
    const int tid = threadIdx.x;
    const int lane = tid & 63, wv = tid >> 6;
    const int b = blockIdx.x;
    float m = 0.f;
    #pragma unroll
    for (int i = 0; i < 4; ++i)
        m = fmaxf(m, bmax[(b << 10) + (i << 8) + tid]);
    #pragma unroll
    for (int off = 1; off < 64; off <<= 1) m = fmaxf(m, __shfl_xor(m, off));
    if (lane == 0) wred[wv] = m;
    __syncthreads();
    if (tid == 0)
        maxrn2[b] = fmaxf(fmaxf(wred[0], wred[1]), fmaxf(wred[2], wred[3]));
}

// ---------------------------------------------------------------------------
// Flash attention partials — producer/consumer wave specialization (verified
// best): waves 0-7 QK (Q in regs), waves 8-15 PV (O in regs). Static-bound
// softmax (Cauchy-Schwarz m_ub) keeps the classes decoupled; K/V/P double-
// buffered; one barrier per window. All intrinsic MFMA (compiler-managed
// hazards). 1024 thr, ~4 waves/SIMD.
// ---------------------------------------------------------------------------
#define M_TILE 128
#define NC 64
#define NCHUNKS 32

#define VS_OFF 32768    // u16 units
#define P_OFF  65536

__device__ __forceinline__ void stage_K(const u16* __restrict__ XT, u16* Kb,
                                        int b, int n0, int wv, int lane)
{
    #pragma unroll
    for (int i = 0; i < 4; ++i) {
        int f = ((i << 3) + wv) << 6;          // wv in 0..7
        int fl = f + lane;
        int r = fl >> 5;                        // key row 0..63
        int gsw = (fl & 31) ^ (r & 15);         // 4-bit pre-swizzle
        gload_lds16(&XT[(size_t)(b * NSEQ + n0 + r) * CDIM + (gsw << 3)], Kb + (f << 3));
    }
}

__device__ __forceinline__ void stage_V(const u16* __restrict__ Vn, u16* Vb,
                                        int b, int n0, int wv, int lane)
{
    #pragma unroll
    for (int i = 0; i < 4; ++i) {
        int f = ((i << 3) + wv) << 6;          // wv in 0..7
        int fl = f + lane;
        int r = fl >> 3;                        // channel row 0..255
        int gsw = (fl & 7) ^ (r & 7);           // 3-bit pre-swizzle
        gload_lds16(&Vn[(size_t)(b * CDIM + r) * NSEQ + n0 + (gsw << 3)], Vb + (f << 3));
    }
}

__global__ __launch_bounds__(1024)
void attn_part_kernel(const u16* __restrict__ XT, const u16* __restrict__ Vn,
                      const float* __restrict__ rn2, const float* __restrict__ maxrn2,
                      float* __restrict__ o0, u16* __restrict__ o1,
                      float* __restrict__ lsum)
{
    __shared__ alignas(16) u16 smem[81920];     // 160 KB exactly

    const int tid = threadIdx.x;
    const int lane = tid & 63;
    const int wid = tid >> 6;                   // 0..15
    const int l31 = lane & 31;
    const int hi = lane >> 5;
    const int bh = blockIdx.x;                  // b*2+h
    const int b = bh >> 1, h = bh & 1;
    const int m0 = blockIdx.y * M_TILE;
    const int nbase = h * (NSEQ / 2);

    if (wid < 8) {
        // ================= QK producer waves =================
        const int qt = wid & 3;                 // q-tile (32 q)
        const int kh = wid >> 2;                // key half (32 keys)
        const int qa = qt * 32 + l31;           // block-local query

        const float mq = sqrtf(rn2[(size_t)b * NSEQ + m0 + qa]) * sqrtf(maxrn2[b]);

        bf16x8 qreg[16];
        {
            const u16* qrow = &XT[(size_t)(b * NSEQ + m0 + qa) * CDIM + (hi << 3)];
            #pragma unroll
            for (int ks = 0; ks < 16; ++ks)
                qreg[ks] = *(const bf16x8*)(qrow + (ks << 4));
        }
        float lrun = 0.f;

        stage_K(XT, smem, b, nbase, wid, lane);        // K[0] -> buf 0
        __syncthreads();                               // B_pre

        for (int w = 0; w <= NCHUNKS; ++w) {
            if (w < NCHUNKS) {
                if (w + 1 < NCHUNKS)
                    stage_K(XT, smem + ((w + 1) & 1) * 16384,
                            b, nbase + (w + 1) * NC, wid, lane);

                const u16* Kc = smem + (w & 1) * 16384;
                u16* Pw = smem + P_OFF + (w & 1) * 8192;

                // ---- QK^T: s = D[key][q] ----
                f32x16 s = {};
                {
                    const int krow = kh * 32 + l31;
                    const u16* kbase = &Kc[krow << 8];
                    const int ksw = krow & 15;
                    #pragma unroll
                    for (int ks = 0; ks < 16; ++ks) {
                        bf16x8 ka = *(const bf16x8*)&kbase[(((ks << 1) + hi) ^ ksw) << 3];
                        s = __builtin_amdgcn_mfma_f32_32x32x16_bf16(ka, qreg[ks], s, 0, 0, 0);
                    }
                }

                // ---- fused exp -> pack -> P store (per 4 keys; low live range) ----
                const int swz = qa & 7;
                float ps = 0.f;
                #pragma unroll
                for (int r4 = 0; r4 < 4; ++r4) {
                    float e0 = __expf(s[r4 * 4 + 0] - mq);
                    float e1 = __expf(s[r4 * 4 + 1] - mq);
                    float e2 = __expf(s[r4 * 4 + 2] - mq);
                    float e3 = __expf(s[r4 * 4 + 3] - mq);
                    ps += (e0 + e1) + (e2 + e3);
                    union { u16 h4[4]; uint2 v; } pk;
                    pk.h4[0] = f2bf(e0); pk.h4[1] = f2bf(e1);
                    pk.h4[2] = f2bf(e2); pk.h4[3] = f2bf(e3);
                    int g = (kh << 2) + r4;
                    *(uint2*)&Pw[(qa << 6) + (((g ^ swz) << 3) | (hi << 2))] = pk.v;
                }
                ps += __shfl_xor(ps, 32);
                lrun += ps;
            }
            __syncthreads();                    // B(w)
        }

        if (lane < 32)
            lsum[(size_t)(((h * 2 + kh) * 4 + b)) * NSEQ + m0 + qa] = lrun;
    } else {
        // ================= PV consumer waves =================
        const int pvw = wid - 8;                // 0..7
        const int qsel = pvw & 1;               // q-tile pair
        const int csel = pvw >> 1;              // c-tile pair (0..3)

        f32x16 o[2][2] = {};

        __syncthreads();                        // B_pre (match)

        for (int w = 0; w <= NCHUNKS; ++w) {
            if (w < NCHUNKS)
                stage_V(Vn, smem + VS_OFF + (w & 1) * 16384,
                        b, nbase + w * NC, pvw, lane);
            if (w >= 1) {
                const u16* Vc = smem + VS_OFF + ((w - 1) & 1) * 16384;
                const u16* Pc = smem + P_OFF + ((w - 1) & 1) * 8192;

                const int q0 = ((qsel << 1) + 0) * 32 + l31;
                const int q1 = ((qsel << 1) + 1) * 32 + l31;
                const int c0 = ((csel << 1) + 0) * 32 + l31;
                const int c1 = ((csel << 1) + 1) * 32 + l31;
                #pragma unroll
                for (int ks = 0; ks < 4; ++ks) {
                    const int gp = (ks << 1) + hi;
                    bf16x8 pb0 = *(const bf16x8*)&Pc[(q0 << 6) + ((gp ^ (q0 & 7)) << 3)];
                    bf16x8 pb1 = *(const bf16x8*)&Pc[(q1 << 6) + ((gp ^ (q1 & 7)) << 3)];
                    bf16x8 va0 = *(const bf16x8*)&Vc[(c0 << 6) + ((gp ^ (c0 & 7)) << 3)];
                    bf16x8 va1 = *(const bf16x8*)&Vc[(c1 << 6) + ((gp ^ (c1 & 7)) << 3)];
                    o[0][0] = __builtin_amdgcn_mfma_f32_32x32x16_bf16(va0, pb0, o[0][0], 0, 0, 0);
                    o[0][1] = __builtin_amdgcn_mfma_f32_32x32x16_bf16(va1, pb0, o[0][1], 0, 0, 0);
                    o[1][0] = __builtin_amdgcn_mfma_f32_32x32x16_bf16(va0, pb1, o[1][0], 0, 0, 0);
                    o[1][1] = __builtin_amdgcn_mfma_f32_32x32x16_bf16(va1, pb1, o[1][1], 0, 0, 0);
                }
            }
            __syncthreads();                    // B(w)
        }

        // ---- partial store: D[c][q] frags -> [b][c][m] directly ----
        #pragma unroll
        for (int qi = 0; qi < 2; ++qi) {
            const int q = m0 + ((qsel << 1) + qi) * 32 + l31;
            #pragma unroll
            for (int cj = 0; cj < 2; ++cj) {
                #pragma unroll
                for (int reg = 0; reg < 16; ++reg) {
                    int c = ((csel << 1) + cj) * 32 + (reg & 3) + ((reg >> 2) << 3) + (hi << 2);
                    size_t oi = ((size_t)(b * CDIM + c)) * NSEQ + q;
                    if (h == 0) o0[oi] = o[qi][cj][reg];
                    else        o1[oi] = f2bf(o[qi][cj][reg]);
                }
            }
        }
    }
}

// ---------------------------------------------------------------------------
// merge: out[i] = g * (O0[i] + O1[i]) / (l00+l01+l10+l11) + ref[i]
// ---------------------------------------------------------------------------
__global__ __launch_bounds__(256)
void merge_kernel(float* __restrict__ out, const u16* __restrict__ o1,
                  const float* __restrict__ lsum, const float* __restrict__ ref,
                  const float* __restrict__ gptr)
{
    const int f = (blockIdx.x << 8) + threadIdx.x;
    const int n4 = f & 1023;
    const int c = (f >> 10) & 255;
    const int b = f >> 18;
    const float g = gptr[0];

    float4 p0 = ((const float4*)out)[f];
    uint2 q1 = *(const uint2*)&o1[((size_t)(b * CDIM + c)) * NSEQ + (n4 << 2)];
    float4 rf = ((const float4*)ref)[f];

    float res[4];
    #pragma unroll
    for (int j = 0; j < 4; ++j) {
        int row = (n4 << 2) + j;
        float l = lsum[(size_t)(0 * 4 + b) * NSEQ + row]
                + lsum[(size_t)(1 * 4 + b) * NSEQ + row]
                + lsum[(size_t)(2 * 4 + b) * NSEQ + row]
                + lsum[(size_t)(3 * 4 + b) * NSEQ + row];
        float rl = 1.0f / l;
        float v0 = ((const float*)&p0)[j];
        unsigned hu = ((j & 1) ? ((&q1.x)[j >> 1] >> 16) : ((&q1.x)[j >> 1] & 0xFFFFu));
        float v1 = __uint_as_float(hu << 16);
        float a = (v0 + v1) * rl;
        res[j] = g * a + ((const float*)&rf)[j];
    }
    ((float4*)out)[f] = *(float4*)res;
}

// ---------------------------------------------------------------------------
extern "C" void kernel_launch(void* const* d_in, const int* in_sizes, int n_in,
                              void* d_out, int out_size, void* d_ws, size_t ws_size,
                              hipStream_t stream)
{
    // dict order: inputs, ref, w1, w2, gamma (dead conv on `inputs` skipped)
    const float* ref = (const float*)d_in[1];
    const float* w1  = (const float*)d_in[2];
    const float* w2  = (const float*)d_in[3];
    const float* gma = (const float*)d_in[4];
    float* out = (float*)d_out;

    u16* XT     = (u16*)d_ws;                          // [B][N][C] bf16 (Q=K)  8.39 MB
    u16* Vn     = XT + (size_t)4 * NSEQ * CDIM;        // [B][C][N] bf16 (V)    8.39 MB
    u16* padded = Vn + (size_t)4 * NSEQ * CDIM;        // [B][4356][256] bf16   8.9 MB (dead after convs)
    u16* wk1    = padded + (size_t)4 * PPIX * CDIM;    // 1.18 MB (dead after convs)
    u16* wk2    = wk1 + (size_t)9 * 65536;             // 1.18 MB (dead after convs)
    // attn-phase reuse of dead regions:
    u16*   o1     = padded;                            // [B][C][N] bf16 partial (8.39 MB)
    float* lsum   = (float*)wk1;                       // [4][B][N] f32 (0.26 MB)
    float* rn2    = (float*)wk2;                       // [B][N] f32 (64 KB)
    float* bmax   = rn2 + 16384;                       // [4096] f32 (16 KB)
    float* maxrn2 = bmax + 4096;                       // [4] f32

    hipMemsetAsync(padded, 0, (size_t)4 * PPIX * CDIM * sizeof(u16), stream);
    pad_transpose_kernel<<<dim3(64, 4, 4), 256, 0, stream>>>(ref, padded);
    w_prepack2_kernel<<<dim3(512), 256, 0, stream>>>(w1, w2, wk1, wk2);

    conv_dual_kernel<<<dim3(2, 64, 4), 256, 0, stream>>>(padded, wk1, wk2, XT, Vn);

    rownorm_kernel<<<dim3(4096), 256, 0, stream>>>(XT, rn2, bmax);        // no atomics
    maxred_kernel<<<dim3(4), 256, 0, stream>>>(bmax, maxrn2);

    attn_part_kernel<<<dim3(8, NSEQ / M_TILE), 1024, 0, stream>>>(XT, Vn, rn2, maxrn2, out, o1, lsum);
    merge_kernel<<<dim3((4 * CDIM * NSEQ / 4) / 256), 256, 0, stream>>>(out, o1, lsum, ref, gma);
}